// Round 6
// baseline (853.490 us; speedup 1.0000x reference)
//
#include <hip/hip_runtime.h>
#include <math.h>

#define Bv 256
#define Dv 38
#define Sv 64
#define SWv 10
#define EPSv 1e-5f

typedef float f4 __attribute__((ext_vector_type(4)));

__device__ __forceinline__ float leaky(float v){ return v > 0.f ? v : 0.01f*v; }
__device__ __forceinline__ float sigm(float v){ return 1.f/(1.f+expf(-v)); }

__device__ __forceinline__ float wred64(float v){
  #pragma unroll
  for (int off=32; off; off>>=1) v += __shfl_xor(v, off, 64);
  return v;
}
__device__ __forceinline__ float wmax64(float v){
  #pragma unroll
  for (int off=32; off; off>>=1) v = fmaxf(v, __shfl_xor(v, off, 64));
  return v;
}

// ---------------- K0: pre-transpose weights into ws ----------------
// wlT[d][c=8][q=16][o=68]: q=ch*4+io <-> f=ch*31+4c+io (zero-pad invalid)
// w1T[d][w=10][o=68]; wv1T[d][o=64][h=36]
__global__ __launch_bounds__(256) void k0_pack(
    const float* __restrict__ Wl, const float* __restrict__ W1,
    const float* __restrict__ Wv1,
    float* __restrict__ wlT, float* __restrict__ w1T, float* __restrict__ wv1T)
{
  int idx = blockIdx.x*256 + threadIdx.x;
  if (idx < 330752) {
    int d = idx / 8704, r = idx % 8704;
    int c = r / 1088, rr = r % 1088;
    int q = rr / 68, o = rr % 68;
    int ch = q >> 2, io = q & 3, fi = 4*c + io;
    float v = 0.f;
    if (o < 64 && fi <= 30) v = Wl[d*7936 + o*124 + ch*31 + fi];
    wlT[idx] = v;
  } else if (idx < 330752 + 25840) {
    int t = idx - 330752;
    int d = t / 680, rr = t % 680;
    int w = rr / 68, o = rr % 68;
    w1T[t] = (o < 64) ? W1[d*640 + o*10 + w] : 0.f;
  } else if (idx < 330752 + 25840 + 87552) {
    int t = idx - 330752 - 25840;
    int d = t / 2304, rr = t % 2304;
    int o = rr / 36, h = rr % 36;
    wv1T[t] = (h < 32) ? Wv1[d*2048 + h*64 + o] : 0.f;
  }
}

// ---------------- K1: 2 batches/block, 256 threads, 4 waves ----------------
__global__ __launch_bounds__(256, 3) void k1_fe4(
    const float* __restrict__ x,
    const float* __restrict__ w1T_all, const float* __restrict__ b1,
    const float* __restrict__ W2, const float* __restrict__ b2,
    const float* __restrict__ wlT_all, const float* __restrict__ bl,
    const float* __restrict__ Wq, const float* __restrict__ bq,
    const float* __restrict__ wv1T_all, const float* __restrict__ bv1,
    const float* __restrict__ lnvg, const float* __restrict__ lnvb,
    const float* __restrict__ Wv2, const float* __restrict__ bv2,
    float* __restrict__ e_ws, float* __restrict__ wq2_ws, float* __restrict__ wv_ws)
{
  __shared__ float sm[12368];
  const int d  = blockIdx.x >> 7;
  const int b0 = (blockIdx.x & 127) * 2;
  const int tid = threadIdx.x;
  const int z = tid >> 7;                 // batch half
  const int t = tid & 127;
  const int tx = t & 15, ty = t >> 4;     // ty 0..7
  const int wz = ty >> 2;                 // wave within half
  const int bd = (b0 + z)*Dv + d;
  const float bq0 = bq[0];

#define PJ(j) ((j) < 4 ? 4*ty + (j) : 32 + 4*ty + ((j)-4))

  // ---- stage consts ----
  if (tid < 64) {
    sm[12032+tid] = b1[d*64+tid];
    sm[12096+tid] = bl[d*64+tid];
    sm[12160+tid] = Wq[tid];
  } else if (tid < 96) {
    int u = tid-64;
    sm[12240+u]=bv1[d*32+u]; sm[12272+u]=lnvg[d*32+u];
    sm[12304+u]=lnvb[d*32+u]; sm[12336+u]=Wv2[d*32+u];
  } else if (tid < 108) sm[12224+(tid-96)] = W2[d*12+(tid-96)];
  else if (tid < 112)   sm[12236+(tid-108)] = b2[d*4+(tid-108)];

  // ---- stage W1T @9792 (170 f4), AT[z] @10472, WL0 @8704 (272 f4) ----
  {
    const f4* s4 = (const f4*)(w1T_all + (size_t)d*680);
    if (tid < 170) ((f4*)&sm[9792])[tid] = s4[tid];
  }
  for (int i = tid; i < 1280; i += 256) {
    int z2 = i / 640, tt = i % 640;
    sm[10472 + z2*680 + (tt%10)*68 + tt/10] =
      x[((size_t)((b0+z2)*Dv + d))*640 + tt];
  }
  const f4* wlsrc = (const f4*)(wlT_all + (size_t)d*8704);
  {
    ((f4*)&sm[8704])[tid] = wlsrc[tid];
    if (tid < 16) ((f4*)&sm[8704])[tid+256] = wlsrc[tid+256];
  }
  __syncthreads();

  // ---- FE1 GEMM: fe[s=4tx+i][o=PJ(j)], K=10 ----
  float fe[4][8];
  #pragma unroll
  for (int i=0;i<4;++i)
    #pragma unroll
    for (int j=0;j<8;++j) fe[i][j]=0.f;
  #pragma unroll
  for (int w = 0; w < 10; ++w) {
    f4 a   = *(const f4*)&sm[10472 + z*680 + w*68 + 4*tx];
    f4 blo = *(const f4*)&sm[9792 + w*68 + 4*ty];
    f4 bhi = *(const f4*)&sm[9792 + w*68 + 32 + 4*ty];
    float bv8[8] = {blo[0],blo[1],blo[2],blo[3],bhi[0],bhi[1],bhi[2],bhi[3]};
    #pragma unroll
    for (int i=0;i<4;++i)
      #pragma unroll
      for (int j=0;j<8;++j) fe[i][j] += a[i]*bv8[j];
  }
  #pragma unroll
  for (int j=0;j<8;++j) {
    int o = PJ(j);
    float bb = sm[12032+o];
    f4 v = {leaky(fe[0][j]+bb), leaky(fe[1][j]+bb), leaky(fe[2][j]+bb), leaky(fe[3][j]+bb)};
    *(f4*)&sm[z*4352 + o*68 + 4*tx] = v;
  }
  __syncthreads();

  // ---- embed: 8 chunks K=16, single-buffer WL (reg prefetch), single MT ----
  float ea[4][8];
  #pragma unroll
  for (int i=0;i<4;++i)
    #pragma unroll
    for (int j=0;j<8;++j) ea[i][j]=0.f;

  f4 wr0, wr1;
  for (int c = 0; c < 8; ++c) {
    if (c > 0) {
      ((f4*)&sm[8704])[tid] = wr0;
      if (tid < 16) ((f4*)&sm[8704])[tid+256] = wr1;
    }
    {
      int s = t & 63, ioh = t >> 6;
      float* mdst = &sm[9792 + z*1088];
      const float* fsrc = &sm[z*4352];
      #pragma unroll
      for (int io2=0; io2<2; ++io2) {
        int io = 2*ioh + io2;
        int fi = 4*c + io;
        if (fi <= 30) {
          int t0 = 2*fi - 1;
          float v0 = (t0 < 0) ? 0.f : fsrc[t0*68+s];
          float v1 = fsrc[(t0+1)*68+s];
          float v2 = fsrc[(t0+2)*68+s];
          float v3 = fsrc[(t0+3)*68+s];
          float v4 = fsrc[(t0+4)*68+s];
          #pragma unroll
          for (int ch=0; ch<4; ++ch) {
            float w0=sm[12224+ch*3], w1=sm[12224+ch*3+1], w2=sm[12224+ch*3+2];
            float bb=sm[12236+ch];
            float ca = bb + v0*w0 + v1*w1 + v2*w2;
            float cb = bb + v1*w0 + v2*w1 + v3*w2;
            float cc = bb + v2*w0 + v3*w1 + v4*w2;
            mdst[(ch*4+io)*68+s] = fmaxf(fmaxf(leaky(ca),leaky(cb)),leaky(cc));
          }
        }
      }
    }
    if (c < 7) {
      wr0 = wlsrc[(c+1)*272 + tid];
      if (tid < 16) wr1 = wlsrc[(c+1)*272 + 256 + tid];
    }
    __syncthreads();
    {
      const float* ma = &sm[9792 + z*1088];
      #pragma unroll
      for (int q=0;q<16;++q){
        f4 a   = *(const f4*)&ma[q*68+4*tx];
        f4 blo = *(const f4*)&sm[8704 + q*68+4*ty];
        f4 bhi = *(const f4*)&sm[8704 + q*68+32+4*ty];
        float bv8[8] = {blo[0],blo[1],blo[2],blo[3],bhi[0],bhi[1],bhi[2],bhi[3]};
        #pragma unroll
        for (int i=0;i<4;++i)
          #pragma unroll
          for (int j=0;j<8;++j) ea[i][j] += a[i]*bv8[j];
      }
    }
    __syncthreads();
  }

  // ---- epilogue: e, eT, wq partials, stage Wv1T ----
  float ev[4][8];
  #pragma unroll
  for (int i=0;i<4;++i)
    #pragma unroll
    for (int j=0;j<8;++j) ev[i][j] = leaky(ea[i][j] + sm[12096 + PJ(j)]);

  {
    float* erow = e_ws + (size_t)bd * 4096;
    #pragma unroll
    for (int i=0;i<4;++i) {
      f4 lo = {ev[i][0],ev[i][1],ev[i][2],ev[i][3]};
      f4 hi = {ev[i][4],ev[i][5],ev[i][6],ev[i][7]};
      *(f4*)&erow[(4*tx+i)*64 + 4*ty] = lo;
      *(f4*)&erow[(4*tx+i)*64 + 32 + 4*ty] = hi;
    }
  }
  #pragma unroll
  for (int j=0;j<8;++j) {
    int o = PJ(j);
    f4 v = {ev[0][j],ev[1][j],ev[2][j],ev[3][j]};
    *(f4*)&sm[z*4352 + o*68 + 4*tx] = v;      // eT over f1T
  }
  #pragma unroll
  for (int i=0;i<4;++i) {
    float p = 0.f;
    #pragma unroll
    for (int j=0;j<8;++j) p += ev[i][j]*sm[12160 + PJ(j)];
    p += __shfl_xor(p, 16);
    p += __shfl_xor(p, 32);
    if ((ty & 3) == 0) sm[11520 + z*128 + wz*64 + 4*tx + i] = p;
  }
  {
    const f4* s4 = (const f4*)(wv1T_all + (size_t)d*2304);
    f4 a0 = s4[tid], a1 = s4[tid+256];
    ((f4*)&sm[8704])[tid] = a0;
    ((f4*)&sm[8704])[tid+256] = a1;
    if (tid < 64) ((f4*)&sm[8704])[tid+512] = s4[tid+512];
  }
  __syncthreads();

  // ---- wq reduce ----
  if (tid < 128) {
    int z2 = tid >> 6, r = tid & 63;
    float p = sm[11520 + z2*128 + r] + sm[11520 + z2*128 + 64 + r];
    wq2_ws[((size_t)(b0+z2)*64 + r)*Dv + d] = sigm(p + bq0);
  }

  // ---- v-GEMM: va[s=4tx+i][h=4ty+j], K=64 ----
  float va[4][4];
  #pragma unroll
  for (int i=0;i<4;++i)
    #pragma unroll
    for (int j=0;j<4;++j) va[i][j]=0.f;
  #pragma unroll 8
  for (int o = 0; o < 64; ++o) {
    f4 a  = *(const f4*)&sm[z*4352 + o*68 + 4*tx];
    f4 bb = *(const f4*)&sm[8704 + o*36 + 4*ty];
    #pragma unroll
    for (int i=0;i<4;++i)
      #pragma unroll
      for (int j=0;j<4;++j) va[i][j] += a[i]*bb[j];
  }
  #pragma unroll
  for (int i=0;i<4;++i)
    #pragma unroll
    for (int j=0;j<4;++j) va[i][j] += sm[12240 + 4*ty + j];

  // ---- LN partials via wave shuffle ----
  #pragma unroll
  for (int i=0;i<4;++i) {
    float ps=0.f, pq=0.f;
    #pragma unroll
    for (int j=0;j<4;++j) { ps += va[i][j]; pq += va[i][j]*va[i][j]; }
    ps += __shfl_xor(ps, 16); ps += __shfl_xor(ps, 32);
    pq += __shfl_xor(pq, 16); pq += __shfl_xor(pq, 32);
    if ((ty & 3) == 0) {
      sm[11008 + z*128 + wz*64 + 4*tx + i] = ps;
      sm[11264 + z*128 + wz*64 + 4*tx + i] = pq;
    }
  }
  __syncthreads();
  if (tid < 128) {
    int z2 = tid >> 6, r = tid & 63;
    float s_ = sm[11008 + z2*128 + r] + sm[11008 + z2*128 + 64 + r];
    float q_ = sm[11264 + z2*128 + r] + sm[11264 + z2*128 + 64 + r];
    float mu = s_*(1.f/32.f);
    float vr = q_*(1.f/32.f) - mu*mu;
    sm[11776 + z2*64 + r] = mu;
    sm[11904 + z2*64 + r] = rsqrtf(vr + EPSv);
  }
  __syncthreads();

  // ---- LN + wv partials ----
  #pragma unroll
  for (int i=0;i<4;++i) {
    float mu = sm[11776 + z*64 + 4*tx + i];
    float rs = sm[11904 + z*64 + 4*tx + i];
    float p = 0.f;
    #pragma unroll
    for (int j=0;j<4;++j) {
      int h = 4*ty + j;
      float vh = leaky(sm[12272+h]*(va[i][j]-mu)*rs + sm[12304+h]);
      p += vh*sm[12336+h];
    }
    p += __shfl_xor(p, 16);
    p += __shfl_xor(p, 32);
    if ((ty & 3) == 0) sm[11520 + z*128 + wz*64 + 4*tx + i] = p;
  }
  __syncthreads();
  if (tid < 128) {
    int z2 = tid >> 6, r = tid & 63;
    float p = sm[11520 + z2*128 + r] + sm[11520 + z2*128 + 64 + r];
    wv_ws[((size_t)((b0+z2)*Dv + d))*64 + r] = fmaxf(p + bv2[d], 0.f);
  }
#undef PJ
}

// ---------------- K2: fused Wb1+LN+Wb2+cumsum+Wk/wq -> score1 ----------------
// 128 threads, 2 (b,d) pairs, 53 KiB LDS -> 3 blocks/CU (6 waves).
// bufA stride 132 (2-way banks on transposed writes); bufB: W1T -> W2T -> WkT.
__global__ __launch_bounds__(128) void k2_fused(
    const float* __restrict__ e_ws,
    const float* __restrict__ Wb1, const float* __restrict__ bb1,
    const float* __restrict__ lng, const float* __restrict__ lnb,
    const float* __restrict__ Wb2, const float* __restrict__ bb2,
    const float* __restrict__ Wk, const float* __restrict__ bk,
    const float* __restrict__ wq2_ws, float* __restrict__ score1)
{
  __shared__ float smem[13568];           // 53 KiB
  float* bufA = smem;                     // [64][132]: EsT -> HnT -> AcmlT
  float* bufB = smem + 8448;              // [4096]: W1T -> W2T -> WkT[64][40]
  float* pts  = smem + 12544;             // [128][2]
  float* ptq  = smem + 12800;             // [128][2]
  float* stmu = smem + 13056;             // [128]
  float* strs = smem + 13184;             // [128]
  float* pt2  = smem + 13312;             // [128][2]

  const int tid = threadIdx.x;
  const int tx = tid & 15;
  const int ty = tid >> 4;                // 0..7
  const int wv = tid >> 6;                // wave id 0..1
  const int bd0 = blockIdx.x * 2;
  const int bd1 = bd0 + 1;

#define RI(i) ((i) < 4 ? 4*tx + (i) : 64 + 4*tx + ((i)-4))
#define PJ(j) ((j) < 4 ? 4*ty + (j) : 32 + 4*ty + ((j)-4))

  // ---- prefetch W2T rows into regs (8 f4, consumed after GEMM1) ----
  f4 w2r[8];
  {
    const f4* W2src = (const f4*)Wb2;
    #pragma unroll
    for (int p = 0; p < 2; ++p)
      #pragma unroll
      for (int q = 0; q < 4; ++q)
        w2r[p*4+q] = W2src[(tx+16*q)*16 + (ty+8*p)];
  }

  // ---- stage EsT (bufA, stride 132), W1T (bufB) ----
  {
    const int r0 = tid & 15, c0 = tid >> 4;      // c0 0..7
    const f4* Esrc  = (const f4*)(e_ws + (size_t)bd0 * 4096);
    #pragma unroll
    for (int p = 0; p < 2; ++p) {
      int oc = c0 + 8*p;
      #pragma unroll
      for (int q = 0; q < 8; ++q) {
        int r = r0 + 16*q;
        f4 v = Esrc[r*16 + oc];
        #pragma unroll
        for (int k = 0; k < 4; ++k) bufA[(4*oc+k)*132 + r] = v[k];
      }
    }
    const f4* W1src = (const f4*)Wb1;
    #pragma unroll
    for (int p = 0; p < 2; ++p) {
      int oc = c0 + 8*p;
      #pragma unroll
      for (int q = 0; q < 4; ++q) {
        int rr = r0 + 16*q;
        f4 v1 = W1src[rr*16 + oc];
        #pragma unroll
        for (int k = 0; k < 4; ++k) bufB[(4*oc+k)*64 + rr] = v1[k];
      }
    }
  }
  __syncthreads();                               // B0

  // per-thread column constants
  float bb1v[8], lngv[8], lnbv[8], bb2v[8];
  #pragma unroll
  for (int j=0;j<8;++j) {
    int p = PJ(j);
    bb1v[j]=bb1[p]; lngv[j]=lng[p]; lnbv[j]=lnb[p]; bb2v[j]=bb2[p];
  }

  // ---- GEMM1: h[r][p] = sum_o E[r][o]*Wb1[p][o] ----
  float h[8][8];
  #pragma unroll
  for (int i=0;i<8;++i)
    #pragma unroll
    for (int j=0;j<8;++j) h[i][j]=0.f;
  for (int o = 0; o < 64; ++o) {
    f4 al = *(const f4*)(bufA + o*132 + 4*tx);
    f4 ah = *(const f4*)(bufA + o*132 + 64 + 4*tx);
    f4 bl = *(const f4*)(bufB + o*64 + 4*ty);
    f4 bh = *(const f4*)(bufB + o*64 + 32 + 4*ty);
    float av[8] = {al[0],al[1],al[2],al[3],ah[0],ah[1],ah[2],ah[3]};
    float bv[8] = {bl[0],bl[1],bl[2],bl[3],bh[0],bh[1],bh[2],bh[3]};
    #pragma unroll
    for (int i=0;i<8;++i)
      #pragma unroll
      for (int j=0;j<8;++j) h[i][j] += av[i]*bv[j];
  }
  #pragma unroll
  for (int i=0;i<8;++i)
    #pragma unroll
    for (int j=0;j<8;++j) h[i][j] += bb1v[j];

  // ---- LN partials via wave shuffle -> pts/ptq [128][2] ----
  #pragma unroll
  for (int i=0;i<8;++i) {
    float ps=0.f, pq=0.f;
    #pragma unroll
    for (int j=0;j<8;++j) { ps += h[i][j]; pq += h[i][j]*h[i][j]; }
    ps += __shfl_xor(ps, 16); ps += __shfl_xor(ps, 32);
    pq += __shfl_xor(pq, 16); pq += __shfl_xor(pq, 32);
    if ((ty & 3) == 0) { pts[RI(i)*2 + wv] = ps; ptq[RI(i)*2 + wv] = pq; }
  }
  __syncthreads();                               // B1

  // ---- W2T write (from regs), stats, Wk prefetch ----
  float wkr[20];
  #pragma unroll
  for (int n = 0; n < 20; ++n) {
    int i2 = tid + 128*n;
    int q = i2/40, k = i2%40;
    wkr[n] = (k < Dv) ? Wk[k*64 + q] : 0.f;
  }
  {
    #pragma unroll
    for (int p = 0; p < 2; ++p) {
      int oc = ty + 8*p;
      #pragma unroll
      for (int q = 0; q < 4; ++q) {
        int rr = tx + 16*q;
        f4 v = w2r[p*4+q];
        #pragma unroll
        for (int k = 0; k < 4; ++k) bufB[(4*oc+k)*64 + rr] = v[k];
      }
    }
  }
  {
    float s = pts[tid*2] + pts[tid*2+1];
    float q = ptq[tid*2] + ptq[tid*2+1];
    float mu = s*(1.f/64.f);
    float va = q*(1.f/64.f) - mu*mu;
    stmu[tid] = mu;
    strs[tid] = rsqrtf(va + EPSv);
  }
  __syncthreads();                               // B2

  // ---- normalize + leaky, write HnT into bufA ----
  {
    float muv[8], rsv[8];
    #pragma unroll
    for (int i=0;i<8;++i) { muv[i]=stmu[RI(i)]; rsv[i]=strs[RI(i)]; }
    #pragma unroll
    for (int i=0;i<8;++i)
      #pragma unroll
      for (int j=0;j<8;++j) {
        float hn = leaky(lngv[j]*(h[i][j]-muv[i])*rsv[i] + lnbv[j]);
        bufA[PJ(j)*132 + RI(i)] = hn;
      }
  }
  __syncthreads();                               // B3

  // ---- GEMM2: g[r][q] = sum_p Hn[r][p]*Wb2[q][p] ----
  float gacc[8][8];
  #pragma unroll
  for (int i=0;i<8;++i)
    #pragma unroll
    for (int j=0;j<8;++j) gacc[i][j]=0.f;
  for (int p = 0; p < 64; ++p) {
    f4 al = *(const f4*)(bufA + p*132 + 4*tx);
    f4 ah = *(const f4*)(bufA + p*132 + 64 + 4*tx);
    f4 bl = *(const f4*)(bufB + p*64 + 4*ty);
    f4 bh = *(const f4*)(bufB + p*64 + 32 + 4*ty);
    float av[8] = {al[0],al[1],al[2],al[3],ah[0],ah[1],ah[2],ah[3]};
    float bv[8] = {bl[0],bl[1],bl[2],bl[3],bh[0],bh[1],bh[2],bh[3]};
    #pragma unroll
    for (int i=0;i<8;++i)
      #pragma unroll
      for (int j=0;j<8;++j) gacc[i][j] += av[i]*bv[j];
  }
  #pragma unroll
  for (int i=0;i<8;++i)
    #pragma unroll
    for (int j=0;j<8;++j) gacc[i][j] = leaky(gacc[i][j] + bb2v[j]);

  // ---- cumsum over s (per 64-row group) via 16-lane segment scan ----
  #pragma unroll
  for (int j=0;j<8;++j) {
    {
      float c0=gacc[0][j], c1=c0+gacc[1][j], c2=c1+gacc[2][j], c3=c2+gacc[3][j];
      float incl = c3;
      #pragma unroll
      for (int dd=1; dd<16; dd<<=1) {
        float t = __shfl_up(incl, dd, 16);
        if ((tid & 15) >= dd) incl += t;
      }
      float ex = incl - c3;
      gacc[0][j]=ex+c0; gacc[1][j]=ex+c1; gacc[2][j]=ex+c2; gacc[3][j]=ex+c3;
    }
    {
      float c0=gacc[4][j], c1=c0+gacc[5][j], c2=c1+gacc[6][j], c3=c2+gacc[7][j];
      float incl = c3;
      #pragma unroll
      for (int dd=1; dd<16; dd<<=1) {
        float t = __shfl_up(incl, dd, 16);
        if ((tid & 15) >= dd) incl += t;
      }
      float ex = incl - c3;
      gacc[4][j]=ex+c0; gacc[5][j]=ex+c1; gacc[6][j]=ex+c2; gacc[7][j]=ex+c3;
    }
  }
  __syncthreads();                               // B4

  // ---- write AcmlT into bufA; WkT (from regs) into bufB ----
  #pragma unroll
  for (int i=0;i<8;++i)
    #pragma unroll
    for (int j=0;j<8;++j) bufA[PJ(j)*132 + RI(i)] = gacc[i][j];
  #pragma unroll
  for (int n = 0; n < 20; ++n) bufB[tid + 128*n] = wkr[n];
  __syncthreads();                               // B5

  // ---- GEMM3: u[r][k] = sum_q acml[r][q]*Wk[k][q] (k<38) ----
  float u[8][4], u2[8][4];
  #pragma unroll
  for (int i=0;i<8;++i)
    #pragma unroll
    for (int j=0;j<4;++j) { u[i][j]=0.f; u2[i][j]=0.f; }
  for (int q = 0; q < 64; ++q) {
    f4 al = *(const f4*)(bufA + q*132 + 4*tx);
    f4 ah = *(const f4*)(bufA + q*132 + 64 + 4*tx);
    f4 b1v = *(const f4*)(bufB + q*40 + 4*ty);
    float av[8] = {al[0],al[1],al[2],al[3],ah[0],ah[1],ah[2],ah[3]};
    #pragma unroll
    for (int i=0;i<8;++i)
      #pragma unroll
      for (int j=0;j<4;++j) u[i][j] += av[i]*b1v[j];
    if (ty < 2) {
      f4 b2v = *(const f4*)(bufB + q*40 + 32 + 4*ty);
      #pragma unroll
      for (int i=0;i<8;++i)
        #pragma unroll
        for (int j=0;j<4;++j) u2[i][j] += av[i]*b2v[j];
    }
  }

  // ---- epilogue: sigm(u+bk)*wq, shfl-reduce over k -> score1 ----
  const int b0g = bd0/Dv, d0g = bd0%Dv, b1g = bd1/Dv, d1g = bd1%Dv;
  #pragma unroll
  for (int i=0;i<8;++i) {
    int s = 4*tx + (i & 3);
    int bb_ = (i<4) ? b0g : b1g;
    const float* wqrow = wq2_ws + ((size_t)bb_*Sv + s)*Dv;
    float p = 0.f;
    #pragma unroll
    for (int j=0;j<4;++j) {
      int k = 4*ty + j;
      p += sigm(u[i][j] + bk[k]) * wqrow[k];
    }
    if (ty < 2) {
      #pragma unroll
      for (int j=0;j<4;++j) {
        int k = 32 + 4*ty + j;
        if (k < Dv) p += sigm(u2[i][j] + bk[k]) * wqrow[k];
      }
    }
    p += __shfl_xor(p, 16); p += __shfl_xor(p, 32);
    if ((ty & 3) == 0) pt2[RI(i)*2 + wv] = p;
  }
  __syncthreads();                               // B6
  {
    int rr = tid;                 // 0..127
    float tot = pt2[rr*2] + pt2[rr*2+1];
    int grp = rr >> 6, s = rr & 63;
    int bb_ = grp ? b1g : b0g;
    int dd_ = grp ? d1g : d0g;
    score1[((size_t)bb_*Sv + s)*Dv + dd_] = tot;
  }
#undef RI
#undef PJ
}

// ---------------- K3: att1 softmax + contributes1/output1 + wq_a ----------------
__global__ __launch_bounds__(256) void k3_att1(
    const float* __restrict__ score1, const float* __restrict__ wv_ws,
    const float* __restrict__ e_ws, const float* __restrict__ Wq2, const float* __restrict__ bq2,
    float* __restrict__ out_c1, float* __restrict__ output1, float* __restrict__ wq_a)
{
  const int blk = blockIdx.x;
  const int b = blk / Sv, s = blk % Sv;
  const int tid = threadIdx.x;
  const int wid = tid>>6, lane = tid&63;
  __shared__ float red[4];

  if (wid==0) {
    const float invsq = 0.16222142113076254f; // 1/sqrt(38)
    float sc = (lane<Dv) ? score1[(b*Sv+s)*Dv+lane]*invsq : -1e30f;
    float mx = wmax64(sc);
    float ex = (lane<Dv) ? expf(sc-mx) : 0.f;
    float den = wred64(ex);
    float att = ex/den;
    float c1 = 0.f;
    if (lane<Dv) {
      c1 = wv_ws[(b*Dv+lane)*Sv+s]*att;
      out_c1[(b*Sv+s)*Dv+lane] = c1;
    }
    float tot = wred64(c1);
    if (lane==0) output1[b*Sv+s] = tot;
  }
  // wq_a[b,s] = sigmoid(ef[b,s]·Wq2 + bq2)
  float p = 0.f;
  for (int idx=tid; idx<Dv*64; idx+=256) {
    int d = idx>>6, o = idx&63;
    p += e_ws[((size_t)(b*Dv+d)*Sv+s)*64+o]*Wq2[idx];
  }
  p = wred64(p);
  if (lane==0) red[wid]=p;
  __syncthreads();
  if (tid==0) wq_a[b*Sv+s] = sigm(red[0]+red[1]+red[2]+red[3]+bq2[0]);
}

// ---------------- K4: per-b 64x64x2432 GEMM + fused score2 ----------------
__global__ __launch_bounds__(256) void k4_gemm(
    const float* __restrict__ e_ws, const float* __restrict__ Wk2, const float* __restrict__ bk2,
    const float* __restrict__ wq_a, float* __restrict__ score2)
{
  const int b = blockIdx.x;
  const int tid = threadIdx.x;
  const int tx = tid & 15, ty = tid >> 4;       // tile coords
  __shared__ float AsT[64*68];
  __shared__ float BsT[64*68];
  __shared__ float pt[64*17];

  float acc[4][4];
  #pragma unroll
  for (int i=0;i<4;++i)
    #pragma unroll
    for (int j=0;j<4;++j) acc[i][j]=0.f;

  const int r0 = tid & 15, oc0 = tid >> 4;      // staging map
  const f4* Bsrc = (const f4*)Wk2;              // row stride 608 f4

  for (int d = 0; d < 38; ++d) {
    const f4* Asrc = (const f4*)(e_ws + ((size_t)(b*Dv+d))*4096);
    #pragma unroll
    for (int q = 0; q < 4; ++q) {
      int r = r0 + 16*q;
      f4 av = Asrc[r*16 + oc0];
      f4 bv = Bsrc[(size_t)r*608 + d*16 + oc0];
      #pragma unroll
      for (int k = 0; k < 4; ++k) {
        AsT[(4*oc0+k)*68 + r] = av[k];
        BsT[(4*oc0+k)*68 + r] = bv[k];
      }
    }
    __syncthreads();
    #pragma unroll 4
    for (int o = 0; o < 64; ++o) {
      f4 a  = *(const f4*)&AsT[o*68 + 4*tx];
      f4 bb = *(const f4*)&BsT[o*68 + 4*ty];
      #pragma unroll
      for (int i=0;i<4;++i)
        #pragma unroll
        for (int j=0;j<4;++j) acc[i][j] += a[i]*bb[j];
    }
    __syncthreads();
  }

  // epilogue: score2[b,t] = sum_s sigm(C[t,s]+bk2[s])*wq_a[b,s]
  #pragma unroll
  for (int i=0;i<4;++i) {
    float p = 0.f;
    #pragma unroll
    for (int j=0;j<4;++j) {
      int s = 4*ty + j;
      p += sigm(acc[i][j] + bk2[s]) * wq_a[b*Sv + s];
    }
    pt[(4*tx+i)*17 + ty] = p;
  }
  __syncthreads();
  if (tid < 64) {
    float tot = 0.f;
    #pragma unroll
    for (int y=0;y<16;++y) tot += pt[tid*17+y];
    score2[b*Sv + tid] = tot;
  }
}

// ---------------- K5: att2 softmax + contributes2/output2 ----------------
__global__ __launch_bounds__(64) void k5_final(
    const float* __restrict__ score2, const float* __restrict__ output1,
    float* __restrict__ out)
{
  const int b = blockIdx.x;
  const int lane = threadIdx.x;
  const float inv = 0.039528470752104741f; // 1/sqrt(640)
  float v = score2[b*Sv+lane]*inv;
  float mx = wmax64(v);
  float ex = expf(v-mx);
  float den = wred64(ex);
  float att = ex/den;
  float c2 = output1[b*Sv+lane]*att;
  out[256 + b*Sv + lane] = c2;     // contributes2
  float tot = wred64(c2);
  if (lane==0) out[b] = tot;       // output2
}

extern "C" void kernel_launch(void* const* d_in, const int* in_sizes, int n_in,
                              void* d_out, int out_size, void* d_ws, size_t ws_size,
                              hipStream_t stream)
{
  const float* x    = (const float*)d_in[0];
  const float* W1   = (const float*)d_in[1];
  const float* b1   = (const float*)d_in[2];
  const float* W2   = (const float*)d_in[3];
  const float* b2   = (const float*)d_in[4];
  const float* Wl   = (const float*)d_in[5];
  const float* bl   = (const float*)d_in[6];
  const float* Wb1  = (const float*)d_in[7];
  const float* bb1  = (const float*)d_in[8];
  const float* lng  = (const float*)d_in[9];
  const float* lnb  = (const float*)d_in[10];
  const float* Wb2  = (const float*)d_in[11];
  const float* bb2  = (const float*)d_in[12];
  const float* Wq   = (const float*)d_in[13];
  const float* bq   = (const float*)d_in[14];
  const float* Wk   = (const float*)d_in[15];
  const float* bk   = (const float*)d_in[16];
  const float* Wv1  = (const float*)d_in[17];
  const float* bv1  = (const float*)d_in[18];
  const float* lnvg = (const float*)d_in[19];
  const float* lnvb = (const float*)d_in[20];
  const float* Wv2  = (const float*)d_in[21];
  const float* bv2  = (const float*)d_in[22];
  const float* Wq2  = (const float*)d_in[23];
  const float* bq2  = (const float*)d_in[24];
  const float* Wk2  = (const float*)d_in[25];
  const float* bk2  = (const float*)d_in[26];

  float* ws = (float*)d_ws;
  float* e_ws  = ws;                                   // B*D*S*64
  float* wq2w  = e_ws + (size_t)Bv*Dv*Sv*64;           // B*S*D  ([b][s][k])
  float* wv_ws = wq2w + (size_t)Bv*Sv*Dv;              // B*D*S
  float* sc1   = wv_ws + (size_t)Bv*Dv*Sv;             // B*S*D
  float* out1  = sc1 + (size_t)Bv*Sv*Dv;               // B*S
  float* wqa   = out1 + (size_t)Bv*Sv;                 // B*S
  float* sc2   = wqa + (size_t)Bv*Sv;                  // B*S
  float* wlT   = sc2 + (size_t)Bv*Sv;                  // 38*8*16*68 = 330752
  float* w1T   = wlT + 330752;                         // 38*10*68 = 25840
  float* wv1T  = w1T + 25840;                          // 38*64*36 = 87552

  float* out = (float*)d_out;
  float* out_c1 = out + 256 + Bv*Sv;                   // contributes1 offset

  hipLaunchKernelGGL(k0_pack, dim3(1736), dim3(256), 0, stream,
    Wl, W1, Wv1, wlT, w1T, wv1T);
  hipLaunchKernelGGL(k1_fe4, dim3(Dv*128), dim3(256), 0, stream,
    x, w1T, b1, W2, b2, wlT, bl, Wq, bq, wv1T, bv1, lnvg, lnvb, Wv2, bv2,
    e_ws, wq2w, wv_ws);
  hipLaunchKernelGGL(k2_fused, dim3(Bv*Dv/2), dim3(128), 0, stream,
    e_ws, Wb1, bb1, lng, lnb, Wb2, bb2, Wk, bk, wq2w, sc1);
  hipLaunchKernelGGL(k3_att1, dim3(Bv*Sv), dim3(256), 0, stream,
    sc1, wv_ws, e_ws, Wq2, bq2, out_c1, out1, wqa);
  hipLaunchKernelGGL(k4_gemm, dim3(Bv), dim3(256), 0, stream,
    e_ws, Wk2, bk2, wqa, sc2);
  hipLaunchKernelGGL(k5_final, dim3(Bv), dim3(64), 0, stream, sc2, out1, out);
}

// Round 7
// 703.605 us; speedup vs baseline: 1.2130x; 1.2130x over previous
//
#include <hip/hip_runtime.h>
#include <math.h>

#define Bv 256
#define Dv 38
#define Sv 64
#define SWv 10
#define EPSv 1e-5f

typedef float f4 __attribute__((ext_vector_type(4)));

__device__ __forceinline__ float leaky(float v){ return v > 0.f ? v : 0.01f*v; }
__device__ __forceinline__ float sigm(float v){ return 1.f/(1.f+expf(-v)); }

__device__ __forceinline__ float wred64(float v){
  #pragma unroll
  for (int off=32; off; off>>=1) v += __shfl_xor(v, off, 64);
  return v;
}
__device__ __forceinline__ float wmax64(float v){
  #pragma unroll
  for (int off=32; off; off>>=1) v = fmaxf(v, __shfl_xor(v, off, 64));
  return v;
}

// ---------------- K0: pre-transpose weights into ws ----------------
// wlT[d][c=8][q=16][o=68]: q=ch*4+io <-> f=ch*31+4c+io (zero-pad invalid)
// w1T[d][w=10][o=68]; wv1T[d][o=64][h=36]
__global__ __launch_bounds__(256) void k0_pack(
    const float* __restrict__ Wl, const float* __restrict__ W1,
    const float* __restrict__ Wv1,
    float* __restrict__ wlT, float* __restrict__ w1T, float* __restrict__ wv1T)
{
  int idx = blockIdx.x*256 + threadIdx.x;
  if (idx < 330752) {
    int d = idx / 8704, r = idx % 8704;
    int c = r / 1088, rr = r % 1088;
    int q = rr / 68, o = rr % 68;
    int ch = q >> 2, io = q & 3, fi = 4*c + io;
    float v = 0.f;
    if (o < 64 && fi <= 30) v = Wl[d*7936 + o*124 + ch*31 + fi];
    wlT[idx] = v;
  } else if (idx < 330752 + 25840) {
    int t = idx - 330752;
    int d = t / 680, rr = t % 680;
    int w = rr / 68, o = rr % 68;
    w1T[t] = (o < 64) ? W1[d*640 + o*10 + w] : 0.f;
  } else if (idx < 330752 + 25840 + 87552) {
    int t = idx - 330752 - 25840;
    int d = t / 2304, rr = t % 2304;
    int o = rr / 36, h = rr % 36;
    wv1T[t] = (h < 32) ? Wv1[d*2048 + h*64 + o] : 0.f;
  }
}

// ---------------- K1: 2 batches/block, 256 threads, 4 waves ----------------
__global__ __launch_bounds__(256, 3) void k1_fe4(
    const float* __restrict__ x,
    const float* __restrict__ w1T_all, const float* __restrict__ b1,
    const float* __restrict__ W2, const float* __restrict__ b2,
    const float* __restrict__ wlT_all, const float* __restrict__ bl,
    const float* __restrict__ Wq, const float* __restrict__ bq,
    const float* __restrict__ wv1T_all, const float* __restrict__ bv1,
    const float* __restrict__ lnvg, const float* __restrict__ lnvb,
    const float* __restrict__ Wv2, const float* __restrict__ bv2,
    float* __restrict__ e_ws, float* __restrict__ wq2_ws, float* __restrict__ wv_ws)
{
  __shared__ float sm[12368];
  const int d  = blockIdx.x >> 7;
  const int b0 = (blockIdx.x & 127) * 2;
  const int tid = threadIdx.x;
  const int z = tid >> 7;                 // batch half
  const int t = tid & 127;
  const int tx = t & 15, ty = t >> 4;     // ty 0..7
  const int wz = ty >> 2;                 // wave within half
  const int bd = (b0 + z)*Dv + d;
  const float bq0 = bq[0];

#define PJ(j) ((j) < 4 ? 4*ty + (j) : 32 + 4*ty + ((j)-4))

  // ---- stage consts ----
  if (tid < 64) {
    sm[12032+tid] = b1[d*64+tid];
    sm[12096+tid] = bl[d*64+tid];
    sm[12160+tid] = Wq[tid];
  } else if (tid < 96) {
    int u = tid-64;
    sm[12240+u]=bv1[d*32+u]; sm[12272+u]=lnvg[d*32+u];
    sm[12304+u]=lnvb[d*32+u]; sm[12336+u]=Wv2[d*32+u];
  } else if (tid < 108) sm[12224+(tid-96)] = W2[d*12+(tid-96)];
  else if (tid < 112)   sm[12236+(tid-108)] = b2[d*4+(tid-108)];

  // ---- stage W1T @9792 (170 f4), AT[z] @10472, WL0 @8704 (272 f4) ----
  {
    const f4* s4 = (const f4*)(w1T_all + (size_t)d*680);
    if (tid < 170) ((f4*)&sm[9792])[tid] = s4[tid];
  }
  for (int i = tid; i < 1280; i += 256) {
    int z2 = i / 640, tt = i % 640;
    sm[10472 + z2*680 + (tt%10)*68 + tt/10] =
      x[((size_t)((b0+z2)*Dv + d))*640 + tt];
  }
  const f4* wlsrc = (const f4*)(wlT_all + (size_t)d*8704);
  {
    ((f4*)&sm[8704])[tid] = wlsrc[tid];
    if (tid < 16) ((f4*)&sm[8704])[tid+256] = wlsrc[tid+256];
  }
  __syncthreads();

  // ---- FE1 GEMM: fe[s=4tx+i][o=PJ(j)], K=10 ----
  float fe[4][8];
  #pragma unroll
  for (int i=0;i<4;++i)
    #pragma unroll
    for (int j=0;j<8;++j) fe[i][j]=0.f;
  #pragma unroll
  for (int w = 0; w < 10; ++w) {
    f4 a   = *(const f4*)&sm[10472 + z*680 + w*68 + 4*tx];
    f4 blo = *(const f4*)&sm[9792 + w*68 + 4*ty];
    f4 bhi = *(const f4*)&sm[9792 + w*68 + 32 + 4*ty];
    float bv8[8] = {blo[0],blo[1],blo[2],blo[3],bhi[0],bhi[1],bhi[2],bhi[3]};
    #pragma unroll
    for (int i=0;i<4;++i)
      #pragma unroll
      for (int j=0;j<8;++j) fe[i][j] += a[i]*bv8[j];
  }
  #pragma unroll
  for (int j=0;j<8;++j) {
    int o = PJ(j);
    float bb = sm[12032+o];
    f4 v = {leaky(fe[0][j]+bb), leaky(fe[1][j]+bb), leaky(fe[2][j]+bb), leaky(fe[3][j]+bb)};
    *(f4*)&sm[z*4352 + o*68 + 4*tx] = v;
  }
  __syncthreads();

  // ---- embed: 8 chunks K=16, single-buffer WL (reg prefetch), single MT ----
  float ea[4][8];
  #pragma unroll
  for (int i=0;i<4;++i)
    #pragma unroll
    for (int j=0;j<8;++j) ea[i][j]=0.f;

  f4 wr0, wr1;
  for (int c = 0; c < 8; ++c) {
    if (c > 0) {
      ((f4*)&sm[8704])[tid] = wr0;
      if (tid < 16) ((f4*)&sm[8704])[tid+256] = wr1;
    }
    {
      int s = t & 63, ioh = t >> 6;
      float* mdst = &sm[9792 + z*1088];
      const float* fsrc = &sm[z*4352];
      #pragma unroll
      for (int io2=0; io2<2; ++io2) {
        int io = 2*ioh + io2;
        int fi = 4*c + io;
        if (fi <= 30) {
          int t0 = 2*fi - 1;
          float v0 = (t0 < 0) ? 0.f : fsrc[t0*68+s];
          float v1 = fsrc[(t0+1)*68+s];
          float v2 = fsrc[(t0+2)*68+s];
          float v3 = fsrc[(t0+3)*68+s];
          float v4 = fsrc[(t0+4)*68+s];
          #pragma unroll
          for (int ch=0; ch<4; ++ch) {
            float w0=sm[12224+ch*3], w1=sm[12224+ch*3+1], w2=sm[12224+ch*3+2];
            float bb=sm[12236+ch];
            float ca = bb + v0*w0 + v1*w1 + v2*w2;
            float cb = bb + v1*w0 + v2*w1 + v3*w2;
            float cc = bb + v2*w0 + v3*w1 + v4*w2;
            mdst[(ch*4+io)*68+s] = fmaxf(fmaxf(leaky(ca),leaky(cb)),leaky(cc));
          }
        }
      }
    }
    if (c < 7) {
      wr0 = wlsrc[(c+1)*272 + tid];
      if (tid < 16) wr1 = wlsrc[(c+1)*272 + 256 + tid];
    }
    __syncthreads();
    {
      const float* ma = &sm[9792 + z*1088];
      #pragma unroll
      for (int q=0;q<16;++q){
        f4 a   = *(const f4*)&ma[q*68+4*tx];
        f4 blo = *(const f4*)&sm[8704 + q*68+4*ty];
        f4 bhi = *(const f4*)&sm[8704 + q*68+32+4*ty];
        float bv8[8] = {blo[0],blo[1],blo[2],blo[3],bhi[0],bhi[1],bhi[2],bhi[3]};
        #pragma unroll
        for (int i=0;i<4;++i)
          #pragma unroll
          for (int j=0;j<8;++j) ea[i][j] += a[i]*bv8[j];
      }
    }
    __syncthreads();
  }

  // ---- epilogue: e, eT, wq partials, stage Wv1T ----
  float ev[4][8];
  #pragma unroll
  for (int i=0;i<4;++i)
    #pragma unroll
    for (int j=0;j<8;++j) ev[i][j] = leaky(ea[i][j] + sm[12096 + PJ(j)]);

  {
    float* erow = e_ws + (size_t)bd * 4096;
    #pragma unroll
    for (int i=0;i<4;++i) {
      f4 lo = {ev[i][0],ev[i][1],ev[i][2],ev[i][3]};
      f4 hi = {ev[i][4],ev[i][5],ev[i][6],ev[i][7]};
      *(f4*)&erow[(4*tx+i)*64 + 4*ty] = lo;
      *(f4*)&erow[(4*tx+i)*64 + 32 + 4*ty] = hi;
    }
  }
  #pragma unroll
  for (int j=0;j<8;++j) {
    int o = PJ(j);
    f4 v = {ev[0][j],ev[1][j],ev[2][j],ev[3][j]};
    *(f4*)&sm[z*4352 + o*68 + 4*tx] = v;      // eT over f1T
  }
  #pragma unroll
  for (int i=0;i<4;++i) {
    float p = 0.f;
    #pragma unroll
    for (int j=0;j<8;++j) p += ev[i][j]*sm[12160 + PJ(j)];
    p += __shfl_xor(p, 16);
    p += __shfl_xor(p, 32);
    if ((ty & 3) == 0) sm[11520 + z*128 + wz*64 + 4*tx + i] = p;
  }
  {
    const f4* s4 = (const f4*)(wv1T_all + (size_t)d*2304);
    f4 a0 = s4[tid], a1 = s4[tid+256];
    ((f4*)&sm[8704])[tid] = a0;
    ((f4*)&sm[8704])[tid+256] = a1;
    if (tid < 64) ((f4*)&sm[8704])[tid+512] = s4[tid+512];
  }
  __syncthreads();

  // ---- wq reduce ----
  if (tid < 128) {
    int z2 = tid >> 6, r = tid & 63;
    float p = sm[11520 + z2*128 + r] + sm[11520 + z2*128 + 64 + r];
    wq2_ws[((size_t)(b0+z2)*64 + r)*Dv + d] = sigm(p + bq0);
  }

  // ---- v-GEMM: va[s=4tx+i][h=4ty+j], K=64 ----
  float va[4][4];
  #pragma unroll
  for (int i=0;i<4;++i)
    #pragma unroll
    for (int j=0;j<4;++j) va[i][j]=0.f;
  #pragma unroll 8
  for (int o = 0; o < 64; ++o) {
    f4 a  = *(const f4*)&sm[z*4352 + o*68 + 4*tx];
    f4 bb = *(const f4*)&sm[8704 + o*36 + 4*ty];
    #pragma unroll
    for (int i=0;i<4;++i)
      #pragma unroll
      for (int j=0;j<4;++j) va[i][j] += a[i]*bb[j];
  }
  #pragma unroll
  for (int i=0;i<4;++i)
    #pragma unroll
    for (int j=0;j<4;++j) va[i][j] += sm[12240 + 4*ty + j];

  // ---- LN partials via wave shuffle ----
  #pragma unroll
  for (int i=0;i<4;++i) {
    float ps=0.f, pq=0.f;
    #pragma unroll
    for (int j=0;j<4;++j) { ps += va[i][j]; pq += va[i][j]*va[i][j]; }
    ps += __shfl_xor(ps, 16); ps += __shfl_xor(ps, 32);
    pq += __shfl_xor(pq, 16); pq += __shfl_xor(pq, 32);
    if ((ty & 3) == 0) {
      sm[11008 + z*128 + wz*64 + 4*tx + i] = ps;
      sm[11264 + z*128 + wz*64 + 4*tx + i] = pq;
    }
  }
  __syncthreads();
  if (tid < 128) {
    int z2 = tid >> 6, r = tid & 63;
    float s_ = sm[11008 + z2*128 + r] + sm[11008 + z2*128 + 64 + r];
    float q_ = sm[11264 + z2*128 + r] + sm[11264 + z2*128 + 64 + r];
    float mu = s_*(1.f/32.f);
    float vr = q_*(1.f/32.f) - mu*mu;
    sm[11776 + z2*64 + r] = mu;
    sm[11904 + z2*64 + r] = rsqrtf(vr + EPSv);
  }
  __syncthreads();

  // ---- LN + wv partials ----
  #pragma unroll
  for (int i=0;i<4;++i) {
    float mu = sm[11776 + z*64 + 4*tx + i];
    float rs = sm[11904 + z*64 + 4*tx + i];
    float p = 0.f;
    #pragma unroll
    for (int j=0;j<4;++j) {
      int h = 4*ty + j;
      float vh = leaky(sm[12272+h]*(va[i][j]-mu)*rs + sm[12304+h]);
      p += vh*sm[12336+h];
    }
    p += __shfl_xor(p, 16);
    p += __shfl_xor(p, 32);
    if ((ty & 3) == 0) sm[11520 + z*128 + wz*64 + 4*tx + i] = p;
  }
  __syncthreads();
  if (tid < 128) {
    int z2 = tid >> 6, r = tid & 63;
    float p = sm[11520 + z2*128 + r] + sm[11520 + z2*128 + 64 + r];
    wv_ws[((size_t)((b0+z2)*Dv + d))*64 + r] = fmaxf(p + bv2[d], 0.f);
  }
#undef PJ
}

// ---------------- K2: fused Wb1+LN+Wb2+cumsum+Wk/wq -> score1 ----------------
// 256 threads / 4 waves, 2 (b,d) pairs. Per-thread tile 4x8 on rows 4tx..4tx+3.
// HnT/AcmlT writes are f4 (ds_write_b128). LDS 55.3 KB -> 2 blocks/CU = 8 waves.
__global__ __launch_bounds__(256) void k2_fused(
    const float* __restrict__ e_ws,
    const float* __restrict__ Wb1, const float* __restrict__ bb1,
    const float* __restrict__ lng, const float* __restrict__ lnb,
    const float* __restrict__ Wb2, const float* __restrict__ bb2,
    const float* __restrict__ Wk, const float* __restrict__ bk,
    const float* __restrict__ wq2_ws, float* __restrict__ score1)
{
  __shared__ float smem[14080];           // 55.0 KiB
  float* bufA = smem;                     // [64][132]: EsT -> HnT -> AcmlT
  float* bufB = smem + 8448;              // [4096]: W1T -> W2T -> WkT[64][40]
  float* pts  = smem + 12544;             // [128][5]  (reused as pt2)
  float* ptq  = smem + 13184;             // [128][5]
  float* stmu = smem + 13824;             // [128]
  float* strs = smem + 13952;             // [128]

  const int tid = threadIdx.x;
  const int tx = tid & 31;                // rows 4tx..4tx+3
  const int ty = tid >> 5;                // 0..7 -> cols
  const int wid = tid >> 6;               // wave 0..3
  const int lane = tid & 63;
  const int bd0 = blockIdx.x * 2;
  const int bd1 = bd0 + 1;

#define PJ(j) ((j) < 4 ? 4*ty + (j) : 32 + 4*ty + ((j)-4))

  const int r0 = tid & 15, c0 = tid >> 4;   // staging map, c0 0..15

  // ---- prefetch W2T rows into regs (4 f4, written after GEMM1) ----
  f4 w2r[4];
  {
    const f4* W2src = (const f4*)Wb2;
    #pragma unroll
    for (int q = 0; q < 4; ++q) w2r[q] = W2src[(r0+16*q)*16 + c0];
  }

  // ---- stage EsT (bufA, stride 132), W1T (bufB) ----
  {
    const f4* Esrc  = (const f4*)(e_ws + (size_t)bd0 * 4096);
    #pragma unroll
    for (int q = 0; q < 8; ++q) {
      int r = r0 + 16*q;
      f4 v = Esrc[r*16 + c0];
      #pragma unroll
      for (int k = 0; k < 4; ++k) bufA[(4*c0+k)*132 + r] = v[k];
    }
    const f4* W1src = (const f4*)Wb1;
    #pragma unroll
    for (int q = 0; q < 4; ++q) {
      int rr = r0 + 16*q;
      f4 v1 = W1src[rr*16 + c0];
      #pragma unroll
      for (int k = 0; k < 4; ++k) bufB[(4*c0+k)*64 + rr] = v1[k];
    }
  }
  __syncthreads();                               // B0

  // per-thread column constants
  float bb1v[8], lngv[8], lnbv[8], bb2v[8];
  #pragma unroll
  for (int j=0;j<8;++j) {
    int p = PJ(j);
    bb1v[j]=bb1[p]; lngv[j]=lng[p]; lnbv[j]=lnb[p]; bb2v[j]=bb2[p];
  }

  // ---- GEMM1: h[r][p] = sum_o E[r][o]*Wb1[p][o], 4x8 tile ----
  float h[4][8];
  #pragma unroll
  for (int i=0;i<4;++i)
    #pragma unroll
    for (int j=0;j<8;++j) h[i][j]=0.f;
  for (int o = 0; o < 64; ++o) {
    f4 a  = *(const f4*)(bufA + o*132 + 4*tx);
    f4 bl = *(const f4*)(bufB + o*64 + 4*ty);
    f4 bh = *(const f4*)(bufB + o*64 + 32 + 4*ty);
    float bv8[8] = {bl[0],bl[1],bl[2],bl[3],bh[0],bh[1],bh[2],bh[3]};
    #pragma unroll
    for (int i=0;i<4;++i)
      #pragma unroll
      for (int j=0;j<8;++j) h[i][j] += a[i]*bv8[j];
  }
  #pragma unroll
  for (int i=0;i<4;++i)
    #pragma unroll
    for (int j=0;j<8;++j) h[i][j] += bb1v[j];

  // ---- LN partials: shfl across ty-pair, 4 wave-partials per row ----
  #pragma unroll
  for (int i=0;i<4;++i) {
    float ps=0.f, pq=0.f;
    #pragma unroll
    for (int j=0;j<8;++j) { ps += h[i][j]; pq += h[i][j]*h[i][j]; }
    ps += __shfl_xor(ps, 32);
    pq += __shfl_xor(pq, 32);
    if (lane < 32) { pts[(4*tx+i)*5 + wid] = ps; ptq[(4*tx+i)*5 + wid] = pq; }
  }
  __syncthreads();                               // B1

  // ---- W2T write (from regs), Wk prefetch, stats ----
  {
    #pragma unroll
    for (int q = 0; q < 4; ++q) {
      int rr = r0 + 16*q;
      f4 v = w2r[q];
      #pragma unroll
      for (int k = 0; k < 4; ++k) bufB[(4*c0+k)*64 + rr] = v[k];
    }
  }
  float wkr[10];
  #pragma unroll
  for (int n = 0; n < 10; ++n) {
    int i2 = tid + 256*n;
    int q = i2/40, k = i2%40;
    wkr[n] = (k < Dv) ? Wk[k*64 + q] : 0.f;
  }
  if (tid < 128) {
    float s = pts[tid*5]+pts[tid*5+1]+pts[tid*5+2]+pts[tid*5+3];
    float q = ptq[tid*5]+ptq[tid*5+1]+ptq[tid*5+2]+ptq[tid*5+3];
    float mu = s*(1.f/64.f);
    float va = q*(1.f/64.f) - mu*mu;
    stmu[tid] = mu;
    strs[tid] = rsqrtf(va + EPSv);
  }
  __syncthreads();                               // B2

  // ---- normalize + leaky, write HnT as f4 rows ----
  {
    float muv[4], rsv[4];
    #pragma unroll
    for (int i=0;i<4;++i) { muv[i]=stmu[4*tx+i]; rsv[i]=strs[4*tx+i]; }
    #pragma unroll
    for (int j=0;j<8;++j) {
      f4 v;
      #pragma unroll
      for (int i=0;i<4;++i)
        v[i] = leaky(lngv[j]*(h[i][j]-muv[i])*rsv[i] + lnbv[j]);
      *(f4*)&bufA[PJ(j)*132 + 4*tx] = v;
    }
  }
  __syncthreads();                               // B3

  // ---- GEMM2: g[r][q] = sum_p Hn[r][p]*Wb2[q][p] ----
  float g[4][8];
  #pragma unroll
  for (int i=0;i<4;++i)
    #pragma unroll
    for (int j=0;j<8;++j) g[i][j]=0.f;
  for (int p = 0; p < 64; ++p) {
    f4 a  = *(const f4*)(bufA + p*132 + 4*tx);
    f4 bl = *(const f4*)(bufB + p*64 + 4*ty);
    f4 bh = *(const f4*)(bufB + p*64 + 32 + 4*ty);
    float bv8[8] = {bl[0],bl[1],bl[2],bl[3],bh[0],bh[1],bh[2],bh[3]};
    #pragma unroll
    for (int i=0;i<4;++i)
      #pragma unroll
      for (int j=0;j<8;++j) g[i][j] += a[i]*bv8[j];
  }
  #pragma unroll
  for (int i=0;i<4;++i)
    #pragma unroll
    for (int j=0;j<8;++j) g[i][j] = leaky(g[i][j] + bb2v[j]);

  // ---- cumsum over s via 16-lane segment scan (rows 4tx..4tx+3 consecutive) ----
  #pragma unroll
  for (int j=0;j<8;++j) {
    float c0_=g[0][j], c1=c0_+g[1][j], c2=c1+g[2][j], c3=c2+g[3][j];
    float incl = c3;
    #pragma unroll
    for (int dd=1; dd<16; dd<<=1) {
      float t = __shfl_up(incl, dd, 16);
      if ((tid & 15) >= dd) incl += t;
    }
    float ex = incl - c3;
    g[0][j]=ex+c0_; g[1][j]=ex+c1; g[2][j]=ex+c2; g[3][j]=ex+c3;
  }
  __syncthreads();                               // B4

  // ---- write AcmlT as f4 rows; WkT (from regs) ----
  #pragma unroll
  for (int j=0;j<8;++j) {
    f4 v = {g[0][j], g[1][j], g[2][j], g[3][j]};
    *(f4*)&bufA[PJ(j)*132 + 4*tx] = v;
  }
  #pragma unroll
  for (int n = 0; n < 10; ++n) bufB[tid + 256*n] = wkr[n];
  __syncthreads();                               // B5

  // ---- GEMM3: u[r][k] = sum_q acml[r][q]*Wk[k][q] (k<38) ----
  float u[4][4], u2[4][4];
  #pragma unroll
  for (int i=0;i<4;++i)
    #pragma unroll
    for (int j=0;j<4;++j) { u[i][j]=0.f; u2[i][j]=0.f; }
  for (int q = 0; q < 64; ++q) {
    f4 a   = *(const f4*)(bufA + q*132 + 4*tx);
    f4 b1v = *(const f4*)(bufB + q*40 + 4*ty);
    #pragma unroll
    for (int i=0;i<4;++i)
      #pragma unroll
      for (int j=0;j<4;++j) u[i][j] += a[i]*b1v[j];
    if (ty < 2) {
      f4 b2v = *(const f4*)(bufB + q*40 + 32 + 4*ty);
      #pragma unroll
      for (int i=0;i<4;++i)
        #pragma unroll
        for (int j=0;j<4;++j) u2[i][j] += a[i]*b2v[j];
    }
  }

  // ---- epilogue: sigm(u+bk)*wq, shfl + [128][5] partials -> score1 ----
  const int b0g = bd0/Dv, d0g = bd0%Dv, b1g = bd1/Dv, d1g = bd1%Dv;
  #pragma unroll
  for (int i=0;i<4;++i) {
    int r = 4*tx + i;
    int s = r & 63;
    int bb_ = (r >> 6) ? b1g : b0g;
    const float* wqrow = wq2_ws + ((size_t)bb_*Sv + s)*Dv;
    float p = 0.f;
    #pragma unroll
    for (int j=0;j<4;++j) {
      int k = 4*ty + j;
      p += sigm(u[i][j] + bk[k]) * wqrow[k];
    }
    if (ty < 2) {
      #pragma unroll
      for (int j=0;j<4;++j) {
        int k = 32 + 4*ty + j;
        if (k < Dv) p += sigm(u2[i][j] + bk[k]) * wqrow[k];
      }
    }
    p += __shfl_xor(p, 32);
    if (lane < 32) pts[r*5 + wid] = p;
  }
  __syncthreads();                               // B6
  if (tid < 128) {
    float tot = pts[tid*5]+pts[tid*5+1]+pts[tid*5+2]+pts[tid*5+3];
    int grp = tid >> 6, s = tid & 63;
    int bb_ = grp ? b1g : b0g;
    int dd_ = grp ? d1g : d0g;
    score1[((size_t)bb_*Sv + s)*Dv + dd_] = tot;
  }
#undef PJ
}

// ---------------- K3: att1 softmax + contributes1/output1 + wq_a ----------------
__global__ __launch_bounds__(256) void k3_att1(
    const float* __restrict__ score1, const float* __restrict__ wv_ws,
    const float* __restrict__ e_ws, const float* __restrict__ Wq2, const float* __restrict__ bq2,
    float* __restrict__ out_c1, float* __restrict__ output1, float* __restrict__ wq_a)
{
  const int blk = blockIdx.x;
  const int b = blk / Sv, s = blk % Sv;
  const int tid = threadIdx.x;
  const int wid = tid>>6, lane = tid&63;
  __shared__ float red[4];

  if (wid==0) {
    const float invsq = 0.16222142113076254f; // 1/sqrt(38)
    float sc = (lane<Dv) ? score1[(b*Sv+s)*Dv+lane]*invsq : -1e30f;
    float mx = wmax64(sc);
    float ex = (lane<Dv) ? expf(sc-mx) : 0.f;
    float den = wred64(ex);
    float att = ex/den;
    float c1 = 0.f;
    if (lane<Dv) {
      c1 = wv_ws[(b*Dv+lane)*Sv+s]*att;
      out_c1[(b*Sv+s)*Dv+lane] = c1;
    }
    float tot = wred64(c1);
    if (lane==0) output1[b*Sv+s] = tot;
  }
  // wq_a[b,s] = sigmoid(ef[b,s]·Wq2 + bq2)
  float p = 0.f;
  for (int idx=tid; idx<Dv*64; idx+=256) {
    int d = idx>>6, o = idx&63;
    p += e_ws[((size_t)(b*Dv+d)*Sv+s)*64+o]*Wq2[idx];
  }
  p = wred64(p);
  if (lane==0) red[wid]=p;
  __syncthreads();
  if (tid==0) wq_a[b*Sv+s] = sigm(red[0]+red[1]+red[2]+red[3]+bq2[0]);
}

// ---------------- K4: per-b 64x64x2432 GEMM + fused score2 ----------------
__global__ __launch_bounds__(256) void k4_gemm(
    const float* __restrict__ e_ws, const float* __restrict__ Wk2, const float* __restrict__ bk2,
    const float* __restrict__ wq_a, float* __restrict__ score2)
{
  const int b = blockIdx.x;
  const int tid = threadIdx.x;
  const int tx = tid & 15, ty = tid >> 4;       // tile coords
  __shared__ float AsT[64*68];
  __shared__ float BsT[64*68];
  __shared__ float pt[64*17];

  float acc[4][4];
  #pragma unroll
  for (int i=0;i<4;++i)
    #pragma unroll
    for (int j=0;j<4;++j) acc[i][j]=0.f;

  const int r0 = tid & 15, oc0 = tid >> 4;      // staging map
  const f4* Bsrc = (const f4*)Wk2;              // row stride 608 f4

  for (int d = 0; d < 38; ++d) {
    const f4* Asrc = (const f4*)(e_ws + ((size_t)(b*Dv+d))*4096);
    #pragma unroll
    for (int q = 0; q < 4; ++q) {
      int r = r0 + 16*q;
      f4 av = Asrc[r*16 + oc0];
      f4 bv = Bsrc[(size_t)r*608 + d*16 + oc0];
      #pragma unroll
      for (int k = 0; k < 4; ++k) {
        AsT[(4*oc0+k)*68 + r] = av[k];
        BsT[(4*oc0+k)*68 + r] = bv[k];
      }
    }
    __syncthreads();
    #pragma unroll 4
    for (int o = 0; o < 64; ++o) {
      f4 a  = *(const f4*)&AsT[o*68 + 4*tx];
      f4 bb = *(const f4*)&BsT[o*68 + 4*ty];
      #pragma unroll
      for (int i=0;i<4;++i)
        #pragma unroll
        for (int j=0;j<4;++j) acc[i][j] += a[i]*bb[j];
    }
    __syncthreads();
  }

  // epilogue: score2[b,t] = sum_s sigm(C[t,s]+bk2[s])*wq_a[b,s]
  #pragma unroll
  for (int i=0;i<4;++i) {
    float p = 0.f;
    #pragma unroll
    for (int j=0;j<4;++j) {
      int s = 4*ty + j;
      p += sigm(acc[i][j] + bk2[s]) * wq_a[b*Sv + s];
    }
    pt[(4*tx+i)*17 + ty] = p;
  }
  __syncthreads();
  if (tid < 64) {
    float tot = 0.f;
    #pragma unroll
    for (int y=0;y<16;++y) tot += pt[tid*17+y];
    score2[b*Sv + tid] = tot;
  }
}

// ---------------- K5: att2 softmax + contributes2/output2 ----------------
__global__ __launch_bounds__(64) void k5_final(
    const float* __restrict__ score2, const float* __restrict__ output1,
    float* __restrict__ out)
{
  const int b = blockIdx.x;
  const int lane = threadIdx.x;
  const float inv = 0.039528470752104741f; // 1/sqrt(640)
  float v = score2[b*Sv+lane]*inv;
  float mx = wmax64(v);
  float ex = expf(v-mx);
  float den = wred64(ex);
  float att = ex/den;
  float c2 = output1[b*Sv+lane]*att;
  out[256 + b*Sv + lane] = c2;     // contributes2
  float tot = wred64(c2);
  if (lane==0) out[b] = tot;       // output2
}

extern "C" void kernel_launch(void* const* d_in, const int* in_sizes, int n_in,
                              void* d_out, int out_size, void* d_ws, size_t ws_size,
                              hipStream_t stream)
{
  const float* x    = (const float*)d_in[0];
  const float* W1   = (const float*)d_in[1];
  const float* b1   = (const float*)d_in[2];
  const float* W2   = (const float*)d_in[3];
  const float* b2   = (const float*)d_in[4];
  const float* Wl   = (const float*)d_in[5];
  const float* bl   = (const float*)d_in[6];
  const float* Wb1  = (const float*)d_in[7];
  const float* bb1  = (const float*)d_in[8];
  const float* lng  = (const float*)d_in[9];
  const float* lnb  = (const float*)d_in[10];
  const float* Wb2  = (const float*)d_in[11];
  const float* bb2  = (const float*)d_in[12];
  const float* Wq   = (const float*)d_in[13];
  const float* bq   = (const float*)d_in[14];
  const float* Wk   = (const float*)d_in[15];
  const float* bk   = (const float*)d_in[16];
  const float* Wv1  = (const float*)d_in[17];
  const float* bv1  = (const float*)d_in[18];
  const float* lnvg = (const float*)d_in[19];
  const float* lnvb = (const float*)d_in[20];
  const float* Wv2  = (const float*)d_in[21];
  const float* bv2  = (const float*)d_in[22];
  const float* Wq2  = (const float*)d_in[23];
  const float* bq2  = (const float*)d_in[24];
  const float* Wk2  = (const float*)d_in[25];
  const float* bk2  = (const float*)d_in[26];

  float* ws = (float*)d_ws;
  float* e_ws  = ws;                                   // B*D*S*64
  float* wq2w  = e_ws + (size_t)Bv*Dv*Sv*64;           // B*S*D  ([b][s][k])
  float* wv_ws = wq2w + (size_t)Bv*Sv*Dv;              // B*D*S
  float* sc1   = wv_ws + (size_t)Bv*Dv*Sv;             // B*S*D
  float* out1  = sc1 + (size_t)Bv*Sv*Dv;               // B*S
  float* wqa   = out1 + (size_t)Bv*Sv;                 // B*S
  float* sc2   = wqa + (size_t)Bv*Sv;                  // B*S
  float* wlT   = sc2 + (size_t)Bv*Sv;                  // 38*8*16*68 = 330752
  float* w1T   = wlT + 330752;                         // 38*10*68 = 25840
  float* wv1T  = w1T + 25840;                          // 38*64*36 = 87552

  float* out = (float*)d_out;
  float* out_c1 = out + 256 + Bv*Sv;                   // contributes1 offset

  hipLaunchKernelGGL(k0_pack, dim3(1736), dim3(256), 0, stream,
    Wl, W1, Wv1, wlT, w1T, wv1T);
  hipLaunchKernelGGL(k1_fe4, dim3(Dv*128), dim3(256), 0, stream,
    x, w1T, b1, W2, b2, wlT, bl, Wq, bq, wv1T, bv1, lnvg, lnvb, Wv2, bv2,
    e_ws, wq2w, wv_ws);
  hipLaunchKernelGGL(k2_fused, dim3(Bv*Dv/2), dim3(256), 0, stream,
    e_ws, Wb1, bb1, lng, lnb, Wb2, bb2, Wk, bk, wq2w, sc1);
  hipLaunchKernelGGL(k3_att1, dim3(Bv*Sv), dim3(256), 0, stream,
    sc1, wv_ws, e_ws, Wq2, bq2, out_c1, out1, wqa);
  hipLaunchKernelGGL(k4_gemm, dim3(Bv), dim3(256), 0, stream,
    e_ws, Wk2, bk2, wqa, sc2);
  hipLaunchKernelGGL(k5_final, dim3(Bv), dim3(64), 0, stream, sc2, out1, out);
}

// Round 8
// 663.545 us; speedup vs baseline: 1.2863x; 1.0604x over previous
//
#include <hip/hip_runtime.h>
#include <math.h>

#define Bv 256
#define Dv 38
#define Sv 64
#define SWv 10
#define EPSv 1e-5f

typedef float f4 __attribute__((ext_vector_type(4)));

__device__ __forceinline__ float leaky(float v){ return v > 0.f ? v : 0.01f*v; }
__device__ __forceinline__ float sigm(float v){ return 1.f/(1.f+expf(-v)); }

__device__ __forceinline__ float wred64(float v){
  #pragma unroll
  for (int off=32; off; off>>=1) v += __shfl_xor(v, off, 64);
  return v;
}
__device__ __forceinline__ float wmax64(float v){
  #pragma unroll
  for (int off=32; off; off>>=1) v = fmaxf(v, __shfl_xor(v, off, 64));
  return v;
}

// ---------------- K0: pre-transpose weights into ws ----------------
__global__ __launch_bounds__(256) void k0_pack(
    const float* __restrict__ Wl, const float* __restrict__ W1,
    const float* __restrict__ Wv1,
    float* __restrict__ wlT, float* __restrict__ w1T, float* __restrict__ wv1T)
{
  int idx = blockIdx.x*256 + threadIdx.x;
  if (idx < 330752) {
    int d = idx / 8704, r = idx % 8704;
    int c = r / 1088, rr = r % 1088;
    int q = rr / 68, o = rr % 68;
    int ch = q >> 2, io = q & 3, fi = 4*c + io;
    float v = 0.f;
    if (o < 64 && fi <= 30) v = Wl[d*7936 + o*124 + ch*31 + fi];
    wlT[idx] = v;
  } else if (idx < 330752 + 25840) {
    int t = idx - 330752;
    int d = t / 680, rr = t % 680;
    int w = rr / 68, o = rr % 68;
    w1T[t] = (o < 64) ? W1[d*640 + o*10 + w] : 0.f;
  } else if (idx < 330752 + 25840 + 87552) {
    int t = idx - 330752 - 25840;
    int d = t / 2304, rr = t % 2304;
    int o = rr / 36, h = rr % 36;
    wv1T[t] = (h < 32) ? Wv1[d*2048 + h*64 + o] : 0.f;
  }
}

// ---------------- K1: 2 batches/block, 256 threads, 4 waves ----------------
// LDS: F1T[z]@z*4352 [64][68]; WL@8704 [16][68]; MT[z]@9792+z*1088;
// FE1: W1T@9792(680), AT[z]@10472+z*680; v-phase: Wv1T@8704(2304),
// vps@11008 vpq@11264 wqp@11520 mu@11776 rs@11904;
// consts@12032: b1,bl@12096,Wq@12160,W2@12224,b2@12236,bv1@12240,
// lnvg@12272,lnvb@12304,Wv2@12336,Wq2@12368; pa-partials@12432(256)
__global__ __launch_bounds__(256, 3) void k1_fe4(
    const float* __restrict__ x,
    const float* __restrict__ w1T_all, const float* __restrict__ b1,
    const float* __restrict__ W2, const float* __restrict__ b2,
    const float* __restrict__ wlT_all, const float* __restrict__ bl,
    const float* __restrict__ Wq, const float* __restrict__ bq,
    const float* __restrict__ wv1T_all, const float* __restrict__ bv1,
    const float* __restrict__ lnvg, const float* __restrict__ lnvb,
    const float* __restrict__ Wv2, const float* __restrict__ bv2,
    const float* __restrict__ Wq2,
    float* __restrict__ e_ws, float* __restrict__ wq2_ws, float* __restrict__ wv_ws,
    float* __restrict__ wqa_p)
{
  __shared__ float sm[12688];
  const int d  = blockIdx.x >> 7;
  const int b0 = (blockIdx.x & 127) * 2;
  const int tid = threadIdx.x;
  const int z = tid >> 7;                 // batch half
  const int t = tid & 127;
  const int tx = t & 15, ty = t >> 4;     // ty 0..7
  const int wz = ty >> 2;                 // wave within half
  const int bd = (b0 + z)*Dv + d;
  const float bq0 = bq[0];

#define PJ(j) ((j) < 4 ? 4*ty + (j) : 32 + 4*ty + ((j)-4))

  // ---- stage consts ----
  if (tid < 64) {
    sm[12032+tid] = b1[d*64+tid];
    sm[12096+tid] = bl[d*64+tid];
    sm[12160+tid] = Wq[tid];
    sm[12368+tid] = Wq2[d*64+tid];
  } else if (tid < 96) {
    int u = tid-64;
    sm[12240+u]=bv1[d*32+u]; sm[12272+u]=lnvg[d*32+u];
    sm[12304+u]=lnvb[d*32+u]; sm[12336+u]=Wv2[d*32+u];
  } else if (tid < 108) sm[12224+(tid-96)] = W2[d*12+(tid-96)];
  else if (tid < 112)   sm[12236+(tid-108)] = b2[d*4+(tid-108)];

  // ---- stage W1T @9792 (170 f4), AT[z] @10472, WL0 @8704 (272 f4) ----
  {
    const f4* s4 = (const f4*)(w1T_all + (size_t)d*680);
    if (tid < 170) ((f4*)&sm[9792])[tid] = s4[tid];
  }
  for (int i = tid; i < 1280; i += 256) {
    int z2 = i / 640, tt = i % 640;
    sm[10472 + z2*680 + (tt%10)*68 + tt/10] =
      x[((size_t)((b0+z2)*Dv + d))*640 + tt];
  }
  const f4* wlsrc = (const f4*)(wlT_all + (size_t)d*8704);
  {
    ((f4*)&sm[8704])[tid] = wlsrc[tid];
    if (tid < 16) ((f4*)&sm[8704])[tid+256] = wlsrc[tid+256];
  }
  __syncthreads();

  // ---- FE1 GEMM: fe[s=4tx+i][o=PJ(j)], K=10 ----
  float fe[4][8];
  #pragma unroll
  for (int i=0;i<4;++i)
    #pragma unroll
    for (int j=0;j<8;++j) fe[i][j]=0.f;
  #pragma unroll
  for (int w = 0; w < 10; ++w) {
    f4 a   = *(const f4*)&sm[10472 + z*680 + w*68 + 4*tx];
    f4 blo = *(const f4*)&sm[9792 + w*68 + 4*ty];
    f4 bhi = *(const f4*)&sm[9792 + w*68 + 32 + 4*ty];
    #pragma unroll
    for (int i=0;i<4;++i)
      #pragma unroll
      for (int j=0;j<8;++j) fe[i][j] += a[i]*((j<4)?blo[j&3]:bhi[j&3]);
  }
  #pragma unroll
  for (int j=0;j<8;++j) {
    int o = PJ(j);
    float bb = sm[12032+o];
    f4 v = {leaky(fe[0][j]+bb), leaky(fe[1][j]+bb), leaky(fe[2][j]+bb), leaky(fe[3][j]+bb)};
    *(f4*)&sm[z*4352 + o*68 + 4*tx] = v;
  }
  __syncthreads();

  // ---- embed: 8 chunks K=16, single-buffer WL (reg prefetch), f4 conv ----
  float ea[4][8];
  #pragma unroll
  for (int i=0;i<4;++i)
    #pragma unroll
    for (int j=0;j<8;++j) ea[i][j]=0.f;

  f4 wr0, wr1;
  for (int c = 0; c < 8; ++c) {
    if (c > 0) {
      ((f4*)&sm[8704])[tid] = wr0;
      if (tid < 16) ((f4*)&sm[8704])[tid+256] = wr1;
    }
    // conv(c) -> MT[z], f4 over 4 s per thread: sg=t&15, io=(t>>4)&3, chh=t>>6
    {
      int sg = t & 15, io = (t >> 4) & 3, chh = t >> 6;
      int fi = 4*c + io;
      if (fi <= 30) {
        int t0 = 2*fi - 1;
        const float* fsrc = &sm[z*4352];
        f4 v0;
        if (fi == 0) { v0[0]=0.f; v0[1]=0.f; v0[2]=0.f; v0[3]=0.f; }
        else         { v0 = *(const f4*)&fsrc[t0*68 + 4*sg]; }
        f4 v1 = *(const f4*)&fsrc[(t0+1)*68 + 4*sg];
        f4 v2 = *(const f4*)&fsrc[(t0+2)*68 + 4*sg];
        f4 v3 = *(const f4*)&fsrc[(t0+3)*68 + 4*sg];
        f4 v4 = *(const f4*)&fsrc[(t0+4)*68 + 4*sg];
        float* mdst = &sm[9792 + z*1088];
        #pragma unroll
        for (int cc2 = 0; cc2 < 2; ++cc2) {
          int ch = 2*chh + cc2;
          float w0=sm[12224+ch*3], w1=sm[12224+ch*3+1], w2=sm[12224+ch*3+2];
          float bb=sm[12236+ch];
          f4 r;
          #pragma unroll
          for (int e2=0;e2<4;++e2) {
            float ca = bb + v0[e2]*w0 + v1[e2]*w1 + v2[e2]*w2;
            float cb = bb + v1[e2]*w0 + v2[e2]*w1 + v3[e2]*w2;
            float cc = bb + v2[e2]*w0 + v3[e2]*w1 + v4[e2]*w2;
            r[e2] = fmaxf(fmaxf(leaky(ca),leaky(cb)),leaky(cc));
          }
          *(f4*)&mdst[(ch*4+io)*68 + 4*sg] = r;
        }
      }
    }
    if (c < 7) {
      wr0 = wlsrc[(c+1)*272 + tid];
      if (tid < 16) wr1 = wlsrc[(c+1)*272 + 256 + tid];
    }
    __syncthreads();
    {
      const float* ma = &sm[9792 + z*1088];
      #pragma unroll
      for (int q=0;q<16;++q){
        f4 a   = *(const f4*)&ma[q*68+4*tx];
        f4 blo = *(const f4*)&sm[8704 + q*68+4*ty];
        f4 bhi = *(const f4*)&sm[8704 + q*68+32+4*ty];
        #pragma unroll
        for (int i=0;i<4;++i)
          #pragma unroll
          for (int j=0;j<8;++j) ea[i][j] += a[i]*((j<4)?blo[j&3]:bhi[j&3]);
      }
    }
    __syncthreads();
  }

  // ---- epilogue: e, eT, wq + wq_a partials, stage Wv1T ----
  float ev[4][8];
  #pragma unroll
  for (int i=0;i<4;++i)
    #pragma unroll
    for (int j=0;j<8;++j) ev[i][j] = leaky(ea[i][j] + sm[12096 + PJ(j)]);

  {
    float* erow = e_ws + (size_t)bd * 4096;
    #pragma unroll
    for (int i=0;i<4;++i) {
      f4 lo = {ev[i][0],ev[i][1],ev[i][2],ev[i][3]};
      f4 hi = {ev[i][4],ev[i][5],ev[i][6],ev[i][7]};
      *(f4*)&erow[(4*tx+i)*64 + 4*ty] = lo;
      *(f4*)&erow[(4*tx+i)*64 + 32 + 4*ty] = hi;
    }
  }
  #pragma unroll
  for (int j=0;j<8;++j) {
    int o = PJ(j);
    f4 v = {ev[0][j],ev[1][j],ev[2][j],ev[3][j]};
    *(f4*)&sm[z*4352 + o*68 + 4*tx] = v;      // eT over f1T
  }
  #pragma unroll
  for (int i=0;i<4;++i) {
    float p = 0.f, pa = 0.f;
    #pragma unroll
    for (int j=0;j<8;++j) {
      p  += ev[i][j]*sm[12160 + PJ(j)];
      pa += ev[i][j]*sm[12368 + PJ(j)];
    }
    p += __shfl_xor(p, 16);  p += __shfl_xor(p, 32);
    pa += __shfl_xor(pa, 16); pa += __shfl_xor(pa, 32);
    if ((ty & 3) == 0) {
      sm[11520 + z*128 + wz*64 + 4*tx + i] = p;
      sm[12432 + z*128 + wz*64 + 4*tx + i] = pa;
    }
  }
  {
    const f4* s4 = (const f4*)(wv1T_all + (size_t)d*2304);
    f4 a0 = s4[tid], a1 = s4[tid+256];
    ((f4*)&sm[8704])[tid] = a0;
    ((f4*)&sm[8704])[tid+256] = a1;
    if (tid < 64) ((f4*)&sm[8704])[tid+512] = s4[tid+512];
  }
  __syncthreads();

  // ---- wq + wq_a-partial reduce ----
  if (tid < 128) {
    int z2 = tid >> 6, r = tid & 63;
    float p = sm[11520 + z2*128 + r] + sm[11520 + z2*128 + 64 + r];
    wq2_ws[((size_t)(b0+z2)*64 + r)*Dv + d] = sigm(p + bq0);
    float pa = sm[12432 + z2*128 + r] + sm[12432 + z2*128 + 64 + r];
    wqa_p[((size_t)(b0+z2)*64 + r)*Dv + d] = pa;
  }

  // ---- v-GEMM: va[s=4tx+i][h=4ty+j], K=64 ----
  float va[4][4];
  #pragma unroll
  for (int i=0;i<4;++i)
    #pragma unroll
    for (int j=0;j<4;++j) va[i][j]=0.f;
  #pragma unroll 8
  for (int o = 0; o < 64; ++o) {
    f4 a  = *(const f4*)&sm[z*4352 + o*68 + 4*tx];
    f4 bb = *(const f4*)&sm[8704 + o*36 + 4*ty];
    #pragma unroll
    for (int i=0;i<4;++i)
      #pragma unroll
      for (int j=0;j<4;++j) va[i][j] += a[i]*bb[j];
  }
  #pragma unroll
  for (int i=0;i<4;++i)
    #pragma unroll
    for (int j=0;j<4;++j) va[i][j] += sm[12240 + 4*ty + j];

  // ---- LN partials via wave shuffle ----
  #pragma unroll
  for (int i=0;i<4;++i) {
    float ps=0.f, pq=0.f;
    #pragma unroll
    for (int j=0;j<4;++j) { ps += va[i][j]; pq += va[i][j]*va[i][j]; }
    ps += __shfl_xor(ps, 16); ps += __shfl_xor(ps, 32);
    pq += __shfl_xor(pq, 16); pq += __shfl_xor(pq, 32);
    if ((ty & 3) == 0) {
      sm[11008 + z*128 + wz*64 + 4*tx + i] = ps;
      sm[11264 + z*128 + wz*64 + 4*tx + i] = pq;
    }
  }
  __syncthreads();
  if (tid < 128) {
    int z2 = tid >> 6, r = tid & 63;
    float s_ = sm[11008 + z2*128 + r] + sm[11008 + z2*128 + 64 + r];
    float q_ = sm[11264 + z2*128 + r] + sm[11264 + z2*128 + 64 + r];
    float mu = s_*(1.f/32.f);
    float vr = q_*(1.f/32.f) - mu*mu;
    sm[11776 + z2*64 + r] = mu;
    sm[11904 + z2*64 + r] = rsqrtf(vr + EPSv);
  }
  __syncthreads();

  // ---- LN + wv partials ----
  #pragma unroll
  for (int i=0;i<4;++i) {
    float mu = sm[11776 + z*64 + 4*tx + i];
    float rs = sm[11904 + z*64 + 4*tx + i];
    float p = 0.f;
    #pragma unroll
    for (int j=0;j<4;++j) {
      int h = 4*ty + j;
      float vh = leaky(sm[12272+h]*(va[i][j]-mu)*rs + sm[12304+h]);
      p += vh*sm[12336+h];
    }
    p += __shfl_xor(p, 16);
    p += __shfl_xor(p, 32);
    if ((ty & 3) == 0) sm[11520 + z*128 + wz*64 + 4*tx + i] = p;
  }
  __syncthreads();
  if (tid < 128) {
    int z2 = tid >> 6, r = tid & 63;
    float p = sm[11520 + z2*128 + r] + sm[11520 + z2*128 + 64 + r];
    wv_ws[((size_t)((b0+z2)*Dv + d))*64 + r] = fmaxf(p + bv2[d], 0.f);
  }
#undef PJ
}

// ---------------- K2: fused Wb1+LN+Wb2+cumsum+Wk/wq -> score1 ----------------
__global__ __launch_bounds__(256) void k2_fused(
    const float* __restrict__ e_ws,
    const float* __restrict__ Wb1, const float* __restrict__ bb1,
    const float* __restrict__ lng, const float* __restrict__ lnb,
    const float* __restrict__ Wb2, const float* __restrict__ bb2,
    const float* __restrict__ Wk, const float* __restrict__ bk,
    const float* __restrict__ wq2_ws, float* __restrict__ score1)
{
  __shared__ float smem[14080];           // 55.0 KiB
  float* bufA = smem;                     // [64][132]: EsT -> HnT -> AcmlT
  float* bufB = smem + 8448;              // [4096]: W1T -> W2T -> WkT[64][40]
  float* pts  = smem + 12544;             // [128][5]  (reused as pt2)
  float* ptq  = smem + 13184;             // [128][5]
  float* stmu = smem + 13824;             // [128]
  float* strs = smem + 13952;             // [128]

  const int tid = threadIdx.x;
  const int tx = tid & 31;                // rows 4tx..4tx+3
  const int ty = tid >> 5;                // 0..7 -> cols
  const int wid = tid >> 6;               // wave 0..3
  const int lane = tid & 63;
  const int bd0 = blockIdx.x * 2;
  const int bd1 = bd0 + 1;

#define PJ(j) ((j) < 4 ? 4*ty + (j) : 32 + 4*ty + ((j)-4))

  const int r0 = tid & 15, c0 = tid >> 4;   // staging map, c0 0..15

  // ---- prefetch W2T rows into regs (4 f4, written after GEMM1) ----
  f4 w2r[4];
  {
    const f4* W2src = (const f4*)Wb2;
    #pragma unroll
    for (int q = 0; q < 4; ++q) w2r[q] = W2src[(r0+16*q)*16 + c0];
  }

  // ---- stage EsT (bufA, stride 132), W1T (bufB) ----
  {
    const f4* Esrc  = (const f4*)(e_ws + (size_t)bd0 * 4096);
    #pragma unroll
    for (int q = 0; q < 8; ++q) {
      int r = r0 + 16*q;
      f4 v = Esrc[r*16 + c0];
      #pragma unroll
      for (int k = 0; k < 4; ++k) bufA[(4*c0+k)*132 + r] = v[k];
    }
    const f4* W1src = (const f4*)Wb1;
    #pragma unroll
    for (int q = 0; q < 4; ++q) {
      int rr = r0 + 16*q;
      f4 v1 = W1src[rr*16 + c0];
      #pragma unroll
      for (int k = 0; k < 4; ++k) bufB[(4*c0+k)*64 + rr] = v1[k];
    }
  }
  __syncthreads();                               // B0

  // per-thread column constants
  float bb1v[8], lngv[8], lnbv[8], bb2v[8];
  #pragma unroll
  for (int j=0;j<8;++j) {
    int p = PJ(j);
    bb1v[j]=bb1[p]; lngv[j]=lng[p]; lnbv[j]=lnb[p]; bb2v[j]=bb2[p];
  }

  // ---- GEMM1: h[r][p] = sum_o E[r][o]*Wb1[p][o], 4x8 tile ----
  float h[4][8];
  #pragma unroll
  for (int i=0;i<4;++i)
    #pragma unroll
    for (int j=0;j<8;++j) h[i][j]=0.f;
  for (int o = 0; o < 64; ++o) {
    f4 a  = *(const f4*)(bufA + o*132 + 4*tx);
    f4 bl = *(const f4*)(bufB + o*64 + 4*ty);
    f4 bh = *(const f4*)(bufB + o*64 + 32 + 4*ty);
    #pragma unroll
    for (int i=0;i<4;++i)
      #pragma unroll
      for (int j=0;j<8;++j) h[i][j] += a[i]*((j<4)?bl[j&3]:bh[j&3]);
  }
  #pragma unroll
  for (int i=0;i<4;++i)
    #pragma unroll
    for (int j=0;j<8;++j) h[i][j] += bb1v[j];

  // ---- LN partials: shfl across ty-pair, 4 wave-partials per row ----
  #pragma unroll
  for (int i=0;i<4;++i) {
    float ps=0.f, pq=0.f;
    #pragma unroll
    for (int j=0;j<8;++j) { ps += h[i][j]; pq += h[i][j]*h[i][j]; }
    ps += __shfl_xor(ps, 32);
    pq += __shfl_xor(pq, 32);
    if (lane < 32) { pts[(4*tx+i)*5 + wid] = ps; ptq[(4*tx+i)*5 + wid] = pq; }
  }
  __syncthreads();                               // B1

  // ---- W2T write (from regs), Wk prefetch, stats ----
  {
    #pragma unroll
    for (int q = 0; q < 4; ++q) {
      int rr = r0 + 16*q;
      f4 v = w2r[q];
      #pragma unroll
      for (int k = 0; k < 4; ++k) bufB[(4*c0+k)*64 + rr] = v[k];
    }
  }
  float wkr[10];
  #pragma unroll
  for (int n = 0; n < 10; ++n) {
    int i2 = tid + 256*n;
    int q = i2/40, k = i2%40;
    wkr[n] = (k < Dv) ? Wk[k*64 + q] : 0.f;
  }
  if (tid < 128) {
    float s = pts[tid*5]+pts[tid*5+1]+pts[tid*5+2]+pts[tid*5+3];
    float q = ptq[tid*5]+ptq[tid*5+1]+ptq[tid*5+2]+ptq[tid*5+3];
    float mu = s*(1.f/64.f);
    float va = q*(1.f/64.f) - mu*mu;
    stmu[tid] = mu;
    strs[tid] = rsqrtf(va + EPSv);
  }
  __syncthreads();                               // B2

  // ---- normalize + leaky, write HnT as f4 rows ----
  {
    float muv[4], rsv[4];
    #pragma unroll
    for (int i=0;i<4;++i) { muv[i]=stmu[4*tx+i]; rsv[i]=strs[4*tx+i]; }
    #pragma unroll
    for (int j=0;j<8;++j) {
      f4 v;
      #pragma unroll
      for (int i=0;i<4;++i)
        v[i] = leaky(lngv[j]*(h[i][j]-muv[i])*rsv[i] + lnbv[j]);
      *(f4*)&bufA[PJ(j)*132 + 4*tx] = v;
    }
  }
  __syncthreads();                               // B3

  // ---- GEMM2: g[r][q] = sum_p Hn[r][p]*Wb2[q][p] ----
  float g[4][8];
  #pragma unroll
  for (int i=0;i<4;++i)
    #pragma unroll
    for (int j=0;j<8;++j) g[i][j]=0.f;
  for (int p = 0; p < 64; ++p) {
    f4 a  = *(const f4*)(bufA + p*132 + 4*tx);
    f4 bl = *(const f4*)(bufB + p*64 + 4*ty);
    f4 bh = *(const f4*)(bufB + p*64 + 32 + 4*ty);
    #pragma unroll
    for (int i=0;i<4;++i)
      #pragma unroll
      for (int j=0;j<8;++j) g[i][j] += a[i]*((j<4)?bl[j&3]:bh[j&3]);
  }
  #pragma unroll
  for (int i=0;i<4;++i)
    #pragma unroll
    for (int j=0;j<8;++j) g[i][j] = leaky(g[i][j] + bb2v[j]);

  // ---- cumsum over s via 16-lane segment scan ----
  #pragma unroll
  for (int j=0;j<8;++j) {
    float c0_=g[0][j], c1=c0_+g[1][j], c2=c1+g[2][j], c3=c2+g[3][j];
    float incl = c3;
    #pragma unroll
    for (int dd=1; dd<16; dd<<=1) {
      float t = __shfl_up(incl, dd, 16);
      if ((tid & 15) >= dd) incl += t;
    }
    float ex = incl - c3;
    g[0][j]=ex+c0_; g[1][j]=ex+c1; g[2][j]=ex+c2; g[3][j]=ex+c3;
  }
  __syncthreads();                               // B4

  // ---- write AcmlT as f4 rows; WkT (from regs) ----
  #pragma unroll
  for (int j=0;j<8;++j) {
    f4 v = {g[0][j], g[1][j], g[2][j], g[3][j]};
    *(f4*)&bufA[PJ(j)*132 + 4*tx] = v;
  }
  #pragma unroll
  for (int n = 0; n < 10; ++n) bufB[tid + 256*n] = wkr[n];
  __syncthreads();                               // B5

  // ---- GEMM3: u[r][k] = sum_q acml[r][q]*Wk[k][q] (k<38) ----
  float u[4][4], u2[4][4];
  #pragma unroll
  for (int i=0;i<4;++i)
    #pragma unroll
    for (int j=0;j<4;++j) { u[i][j]=0.f; u2[i][j]=0.f; }
  for (int q = 0; q < 64; ++q) {
    f4 a   = *(const f4*)(bufA + q*132 + 4*tx);
    f4 b1v = *(const f4*)(bufB + q*40 + 4*ty);
    #pragma unroll
    for (int i=0;i<4;++i)
      #pragma unroll
      for (int j=0;j<4;++j) u[i][j] += a[i]*b1v[j];
    if (ty < 2) {
      f4 b2v = *(const f4*)(bufB + q*40 + 32 + 4*ty);
      #pragma unroll
      for (int i=0;i<4;++i)
        #pragma unroll
        for (int j=0;j<4;++j) u2[i][j] += a[i]*b2v[j];
    }
  }

  // ---- epilogue: sigm(u+bk)*wq, shfl + [128][5] partials -> score1 ----
  const int b0g = bd0/Dv, d0g = bd0%Dv, b1g = bd1/Dv, d1g = bd1%Dv;
  #pragma unroll
  for (int i=0;i<4;++i) {
    int r = 4*tx + i;
    int s = r & 63;
    int bb_ = (r >> 6) ? b1g : b0g;
    const float* wqrow = wq2_ws + ((size_t)bb_*Sv + s)*Dv;
    float p = 0.f;
    #pragma unroll
    for (int j=0;j<4;++j) {
      int k = 4*ty + j;
      p += sigm(u[i][j] + bk[k]) * wqrow[k];
    }
    if (ty < 2) {
      #pragma unroll
      for (int j=0;j<4;++j) {
        int k = 32 + 4*ty + j;
        if (k < Dv) p += sigm(u2[i][j] + bk[k]) * wqrow[k];
      }
    }
    p += __shfl_xor(p, 32);
    if (lane < 32) pts[r*5 + wid] = p;
  }
  __syncthreads();                               // B6
  if (tid < 128) {
    float tot = pts[tid*5]+pts[tid*5+1]+pts[tid*5+2]+pts[tid*5+3];
    int grp = tid >> 6, s = tid & 63;
    int bb_ = grp ? b1g : b0g;
    int dd_ = grp ? d1g : d0g;
    score1[((size_t)bb_*Sv + s)*Dv + dd_] = tot;
  }
#undef PJ
}

// ---------------- K3: att1 softmax + contributes1/output1 + wq_a (64 thr) ----------------
__global__ __launch_bounds__(64) void k3_att1(
    const float* __restrict__ score1, const float* __restrict__ wv_ws,
    const float* __restrict__ wqa_p, const float* __restrict__ bq2,
    float* __restrict__ out_c1, float* __restrict__ output1, float* __restrict__ wq_a)
{
  const int blk = blockIdx.x;
  const int b = blk / Sv, s = blk % Sv;
  const int lane = threadIdx.x;

  const float invsq = 0.16222142113076254f; // 1/sqrt(38)
  float sc = (lane<Dv) ? score1[(b*Sv+s)*Dv+lane]*invsq : -1e30f;
  float mx = wmax64(sc);
  float ex = (lane<Dv) ? expf(sc-mx) : 0.f;
  float den = wred64(ex);
  float att = ex/den;
  float c1 = 0.f;
  if (lane<Dv) {
    c1 = wv_ws[(b*Dv+lane)*Sv+s]*att;
    out_c1[(b*Sv+s)*Dv+lane] = c1;
  }
  float tot = wred64(c1);
  if (lane==0) output1[b*Sv+s] = tot;

  // wq_a from k1's partials
  float p = (lane < Dv) ? wqa_p[((size_t)b*Sv + s)*Dv + lane] : 0.f;
  p = wred64(p);
  if (lane==0) wq_a[b*Sv+s] = sigm(p + bq2[0]);
}

// ---------------- K4: per-b 64x64x2432 GEMM + fused score2 ----------------
__global__ __launch_bounds__(256) void k4_gemm(
    const float* __restrict__ e_ws, const float* __restrict__ Wk2, const float* __restrict__ bk2,
    const float* __restrict__ wq_a, float* __restrict__ score2)
{
  const int b = blockIdx.x;
  const int tid = threadIdx.x;
  const int tx = tid & 15, ty = tid >> 4;       // tile coords
  __shared__ float AsT[64*68];
  __shared__ float BsT[64*68];
  __shared__ float pt[64*17];

  float acc[4][4];
  #pragma unroll
  for (int i=0;i<4;++i)
    #pragma unroll
    for (int j=0;j<4;++j) acc[i][j]=0.f;

  const int r0 = tid & 15, oc0 = tid >> 4;      // staging map
  const f4* Bsrc = (const f4*)Wk2;              // row stride 608 f4

  for (int d = 0; d < 38; ++d) {
    const f4* Asrc = (const f4*)(e_ws + ((size_t)(b*Dv+d))*4096);
    #pragma unroll
    for (int q = 0; q < 4; ++q) {
      int r = r0 + 16*q;
      f4 av = Asrc[r*16 + oc0];
      f4 bv = Bsrc[(size_t)r*608 + d*16 + oc0];
      #pragma unroll
      for (int k = 0; k < 4; ++k) {
        AsT[(4*oc0+k)*68 + r] = av[k];
        BsT[(4*oc0+k)*68 + r] = bv[k];
      }
    }
    __syncthreads();
    #pragma unroll 4
    for (int o = 0; o < 64; ++o) {
      f4 a  = *(const f4*)&AsT[o*68 + 4*tx];
      f4 bb = *(const f4*)&BsT[o*68 + 4*ty];
      #pragma unroll
      for (int i=0;i<4;++i)
        #pragma unroll
        for (int j=0;j<4;++j) acc[i][j] += a[i]*bb[j];
    }
    __syncthreads();
  }

  // epilogue: score2[b,t] = sum_s sigm(C[t,s]+bk2[s])*wq_a[b,s]
  #pragma unroll
  for (int i=0;i<4;++i) {
    float p = 0.f;
    #pragma unroll
    for (int j=0;j<4;++j) {
      int s = 4*ty + j;
      p += sigm(acc[i][j] + bk2[s]) * wq_a[b*Sv + s];
    }
    pt[(4*tx+i)*17 + ty] = p;
  }
  __syncthreads();
  if (tid < 64) {
    float tot = 0.f;
    #pragma unroll
    for (int y=0;y<16;++y) tot += pt[tid*17+y];
    score2[b*Sv + tid] = tot;
  }
}

// ---------------- K5: att2 softmax + contributes2/output2 ----------------
__global__ __launch_bounds__(64) void k5_final(
    const float* __restrict__ score2, const float* __restrict__ output1,
    float* __restrict__ out)
{
  const int b = blockIdx.x;
  const int lane = threadIdx.x;
  const float inv = 0.039528470752104741f; // 1/sqrt(640)
  float v = score2[b*Sv+lane]*inv;
  float mx = wmax64(v);
  float ex = expf(v-mx);
  float den = wred64(ex);
  float att = ex/den;
  float c2 = output1[b*Sv+lane]*att;
  out[256 + b*Sv + lane] = c2;     // contributes2
  float tot = wred64(c2);
  if (lane==0) out[b] = tot;       // output2
}

extern "C" void kernel_launch(void* const* d_in, const int* in_sizes, int n_in,
                              void* d_out, int out_size, void* d_ws, size_t ws_size,
                              hipStream_t stream)
{
  const float* x    = (const float*)d_in[0];
  const float* W1   = (const float*)d_in[1];
  const float* b1   = (const float*)d_in[2];
  const float* W2   = (const float*)d_in[3];
  const float* b2   = (const float*)d_in[4];
  const float* Wl   = (const float*)d_in[5];
  const float* bl   = (const float*)d_in[6];
  const float* Wb1  = (const float*)d_in[7];
  const float* bb1  = (const float*)d_in[8];
  const float* lng  = (const float*)d_in[9];
  const float* lnb  = (const float*)d_in[10];
  const float* Wb2  = (const float*)d_in[11];
  const float* bb2  = (const float*)d_in[12];
  const float* Wq   = (const float*)d_in[13];
  const float* bq   = (const float*)d_in[14];
  const float* Wk   = (const float*)d_in[15];
  const float* bk   = (const float*)d_in[16];
  const float* Wv1  = (const float*)d_in[17];
  const float* bv1  = (const float*)d_in[18];
  const float* lnvg = (const float*)d_in[19];
  const float* lnvb = (const float*)d_in[20];
  const float* Wv2  = (const float*)d_in[21];
  const float* bv2  = (const float*)d_in[22];
  const float* Wq2  = (const float*)d_in[23];
  const float* bq2  = (const float*)d_in[24];
  const float* Wk2  = (const float*)d_in[25];
  const float* bk2  = (const float*)d_in[26];

  float* ws = (float*)d_ws;
  float* e_ws  = ws;                                   // B*D*S*64
  float* wq2w  = e_ws + (size_t)Bv*Dv*Sv*64;           // B*S*D  ([b][s][k])
  float* wv_ws = wq2w + (size_t)Bv*Sv*Dv;              // B*D*S
  float* sc1   = wv_ws + (size_t)Bv*Dv*Sv;             // B*S*D
  float* out1  = sc1 + (size_t)Bv*Sv*Dv;               // B*S
  float* wqa   = out1 + (size_t)Bv*Sv;                 // B*S
  float* sc2   = wqa + (size_t)Bv*Sv;                  // B*S
  float* wlT   = sc2 + (size_t)Bv*Sv;                  // 38*8*16*68 = 330752
  float* w1T   = wlT + 330752;                         // 38*10*68 = 25840
  float* wv1T  = w1T + 25840;                          // 38*64*36 = 87552
  float* wqap  = wv1T + 87552;                         // B*S*D = 622592

  float* out = (float*)d_out;
  float* out_c1 = out + 256 + Bv*Sv;                   // contributes1 offset

  hipLaunchKernelGGL(k0_pack, dim3(1736), dim3(256), 0, stream,
    Wl, W1, Wv1, wlT, w1T, wv1T);
  hipLaunchKernelGGL(k1_fe4, dim3(Dv*128), dim3(256), 0, stream,
    x, w1T, b1, W2, b2, wlT, bl, Wq, bq, wv1T, bv1, lnvg, lnvb, Wv2, bv2,
    Wq2, e_ws, wq2w, wv_ws, wqap);
  hipLaunchKernelGGL(k2_fused, dim3(Bv*Dv/2), dim3(256), 0, stream,
    e_ws, Wb1, bb1, lng, lnb, Wb2, bb2, Wk, bk, wq2w, sc1);
  hipLaunchKernelGGL(k3_att1, dim3(Bv*Sv), dim3(64), 0, stream,
    sc1, wv_ws, wqap, bq2, out_c1, out1, wqa);
  hipLaunchKernelGGL(k4_gemm, dim3(Bv), dim3(256), 0, stream,
    e_ws, Wk2, bk2, wqa, sc2);
  hipLaunchKernelGGL(k5_final, dim3(Bv), dim3(64), 0, stream, sc2, out1, out);
}

// Round 9
// 600.734 us; speedup vs baseline: 1.4207x; 1.1046x over previous
//
#include <hip/hip_runtime.h>
#include <math.h>

#define Bv 256
#define Dv 38
#define Sv 64
#define SWv 10
#define EPSv 1e-5f

typedef float f4 __attribute__((ext_vector_type(4)));

__device__ __forceinline__ float leaky(float v){ return v > 0.f ? v : 0.01f*v; }
__device__ __forceinline__ float sigm(float v){ return 1.f/(1.f+expf(-v)); }

__device__ __forceinline__ float wred64(float v){
  #pragma unroll
  for (int off=32; off; off>>=1) v += __shfl_xor(v, off, 64);
  return v;
}
__device__ __forceinline__ float wmax64(float v){
  #pragma unroll
  for (int off=32; off; off>>=1) v = fmaxf(v, __shfl_xor(v, off, 64));
  return v;
}

// ---------------- K0: pre-transpose weights into ws ----------------
// wlT[d][c=8][q=16][o=68]; w1T[d][w=10][o=68]; wv1T[d][o=64][h=36];
// wb1T[o][p]=Wb1[p][o]; wb2T[p][q]=Wb2[q][p]; wkT[q][40:k]=Wk[k][q];
// wk2T[d][o][s]=Wk2[s][d*64+o]
__global__ __launch_bounds__(256) void k0_pack(
    const float* __restrict__ Wl, const float* __restrict__ W1,
    const float* __restrict__ Wv1, const float* __restrict__ Wb1,
    const float* __restrict__ Wb2, const float* __restrict__ Wk,
    const float* __restrict__ Wk2,
    float* __restrict__ wlT, float* __restrict__ w1T, float* __restrict__ wv1T,
    float* __restrict__ wb1T, float* __restrict__ wb2T, float* __restrict__ wkT,
    float* __restrict__ wk2T)
{
  int idx = blockIdx.x*256 + threadIdx.x;
  if (idx < 330752) {
    int d = idx / 8704, r = idx % 8704;
    int c = r / 1088, rr = r % 1088;
    int q = rr / 68, o = rr % 68;
    int ch = q >> 2, io = q & 3, fi = 4*c + io;
    float v = 0.f;
    if (o < 64 && fi <= 30) v = Wl[d*7936 + o*124 + ch*31 + fi];
    wlT[idx] = v;
  } else if (idx < 356592) {
    int t = idx - 330752;
    int d = t / 680, rr = t % 680;
    int w = rr / 68, o = rr % 68;
    w1T[t] = (o < 64) ? W1[d*640 + o*10 + w] : 0.f;
  } else if (idx < 444144) {
    int t = idx - 356592;
    int d = t / 2304, rr = t % 2304;
    int o = rr / 36, h = rr % 36;
    wv1T[t] = (h < 32) ? Wv1[d*2048 + h*64 + o] : 0.f;
  } else if (idx < 448240) {
    int t = idx - 444144;
    int o = t >> 6, p = t & 63;
    wb1T[t] = Wb1[p*64 + o];
  } else if (idx < 452336) {
    int t = idx - 448240;
    int p = t >> 6, q = t & 63;
    wb2T[t] = Wb2[q*64 + p];
  } else if (idx < 454896) {
    int t = idx - 452336;
    int q = t / 40, k = t % 40;
    wkT[t] = (k < Dv) ? Wk[k*64 + q] : 0.f;
  } else if (idx < 610544) {
    int t = idx - 454896;
    int d = t / 4096, rr = t % 4096;
    int o = rr >> 6, s = rr & 63;
    wk2T[t] = Wk2[s*2432 + d*64 + o];
  }
}

// ---------------- K1: 2 batches/block, 256 threads, 4 waves ----------------
__global__ __launch_bounds__(256, 3) void k1_fe4(
    const float* __restrict__ x,
    const float* __restrict__ w1T_all, const float* __restrict__ b1,
    const float* __restrict__ W2, const float* __restrict__ b2,
    const float* __restrict__ wlT_all, const float* __restrict__ bl,
    const float* __restrict__ Wq, const float* __restrict__ bq,
    const float* __restrict__ wv1T_all, const float* __restrict__ bv1,
    const float* __restrict__ lnvg, const float* __restrict__ lnvb,
    const float* __restrict__ Wv2, const float* __restrict__ bv2,
    const float* __restrict__ Wq2,
    float* __restrict__ e_wsT, float* __restrict__ wq2_ws, float* __restrict__ wv_ws,
    float* __restrict__ wqa_p)
{
  __shared__ float sm[12688];
  const int d  = blockIdx.x >> 7;
  const int b0 = (blockIdx.x & 127) * 2;
  const int tid = threadIdx.x;
  const int z = tid >> 7;                 // batch half
  const int t = tid & 127;
  const int tx = t & 15, ty = t >> 4;     // ty 0..7
  const int wz = ty >> 2;                 // wave within half
  const int bd = (b0 + z)*Dv + d;
  const float bq0 = bq[0];

#define PJ(j) ((j) < 4 ? 4*ty + (j) : 32 + 4*ty + ((j)-4))

  // ---- stage consts ----
  if (tid < 64) {
    sm[12032+tid] = b1[d*64+tid];
    sm[12096+tid] = bl[d*64+tid];
    sm[12160+tid] = Wq[tid];
    sm[12368+tid] = Wq2[d*64+tid];
  } else if (tid < 96) {
    int u = tid-64;
    sm[12240+u]=bv1[d*32+u]; sm[12272+u]=lnvg[d*32+u];
    sm[12304+u]=lnvb[d*32+u]; sm[12336+u]=Wv2[d*32+u];
  } else if (tid < 108) sm[12224+(tid-96)] = W2[d*12+(tid-96)];
  else if (tid < 112)   sm[12236+(tid-108)] = b2[d*4+(tid-108)];

  // ---- stage W1T @9792 (170 f4), AT[z] @10472, WL0 @8704 (272 f4) ----
  {
    const f4* s4 = (const f4*)(w1T_all + (size_t)d*680);
    if (tid < 170) ((f4*)&sm[9792])[tid] = s4[tid];
  }
  for (int i = tid; i < 1280; i += 256) {
    int z2 = i / 640, tt = i % 640;
    sm[10472 + z2*680 + (tt%10)*68 + tt/10] =
      x[((size_t)((b0+z2)*Dv + d))*640 + tt];
  }
  const f4* wlsrc = (const f4*)(wlT_all + (size_t)d*8704);
  {
    ((f4*)&sm[8704])[tid] = wlsrc[tid];
    if (tid < 16) ((f4*)&sm[8704])[tid+256] = wlsrc[tid+256];
  }
  __syncthreads();

  // ---- FE1 GEMM: fe[s=4tx+i][o=PJ(j)], K=10 ----
  float fe[4][8];
  #pragma unroll
  for (int i=0;i<4;++i)
    #pragma unroll
    for (int j=0;j<8;++j) fe[i][j]=0.f;
  #pragma unroll
  for (int w = 0; w < 10; ++w) {
    f4 a   = *(const f4*)&sm[10472 + z*680 + w*68 + 4*tx];
    f4 blo = *(const f4*)&sm[9792 + w*68 + 4*ty];
    f4 bhi = *(const f4*)&sm[9792 + w*68 + 32 + 4*ty];
    #pragma unroll
    for (int i=0;i<4;++i)
      #pragma unroll
      for (int j=0;j<8;++j) fe[i][j] += a[i]*((j<4)?blo[j&3]:bhi[j&3]);
  }
  #pragma unroll
  for (int j=0;j<8;++j) {
    int o = PJ(j);
    float bb = sm[12032+o];
    f4 v = {leaky(fe[0][j]+bb), leaky(fe[1][j]+bb), leaky(fe[2][j]+bb), leaky(fe[3][j]+bb)};
    *(f4*)&sm[z*4352 + o*68 + 4*tx] = v;
  }
  __syncthreads();

  // ---- embed: 8 chunks K=16, single-buffer WL (reg prefetch), f4 conv ----
  float ea[4][8];
  #pragma unroll
  for (int i=0;i<4;++i)
    #pragma unroll
    for (int j=0;j<8;++j) ea[i][j]=0.f;

  f4 wr0, wr1;
  for (int c = 0; c < 8; ++c) {
    if (c > 0) {
      ((f4*)&sm[8704])[tid] = wr0;
      if (tid < 16) ((f4*)&sm[8704])[tid+256] = wr1;
    }
    {
      int sg = t & 15, io = (t >> 4) & 3, chh = t >> 6;
      int fi = 4*c + io;
      if (fi <= 30) {
        int t0 = 2*fi - 1;
        const float* fsrc = &sm[z*4352];
        f4 v0;
        if (fi == 0) { v0[0]=0.f; v0[1]=0.f; v0[2]=0.f; v0[3]=0.f; }
        else         { v0 = *(const f4*)&fsrc[t0*68 + 4*sg]; }
        f4 v1 = *(const f4*)&fsrc[(t0+1)*68 + 4*sg];
        f4 v2 = *(const f4*)&fsrc[(t0+2)*68 + 4*sg];
        f4 v3 = *(const f4*)&fsrc[(t0+3)*68 + 4*sg];
        f4 v4 = *(const f4*)&fsrc[(t0+4)*68 + 4*sg];
        float* mdst = &sm[9792 + z*1088];
        #pragma unroll
        for (int cc2 = 0; cc2 < 2; ++cc2) {
          int ch = 2*chh + cc2;
          float w0=sm[12224+ch*3], w1=sm[12224+ch*3+1], w2=sm[12224+ch*3+2];
          float bb=sm[12236+ch];
          f4 r;
          #pragma unroll
          for (int e2=0;e2<4;++e2) {
            float ca = bb + v0[e2]*w0 + v1[e2]*w1 + v2[e2]*w2;
            float cb = bb + v1[e2]*w0 + v2[e2]*w1 + v3[e2]*w2;
            float cc = bb + v2[e2]*w0 + v3[e2]*w1 + v4[e2]*w2;
            r[e2] = fmaxf(fmaxf(leaky(ca),leaky(cb)),leaky(cc));
          }
          *(f4*)&mdst[(ch*4+io)*68 + 4*sg] = r;
        }
      }
    }
    if (c < 7) {
      wr0 = wlsrc[(c+1)*272 + tid];
      if (tid < 16) wr1 = wlsrc[(c+1)*272 + 256 + tid];
    }
    __syncthreads();
    {
      const float* ma = &sm[9792 + z*1088];
      #pragma unroll
      for (int q=0;q<16;++q){
        f4 a   = *(const f4*)&ma[q*68+4*tx];
        f4 blo = *(const f4*)&sm[8704 + q*68+4*ty];
        f4 bhi = *(const f4*)&sm[8704 + q*68+32+4*ty];
        #pragma unroll
        for (int i=0;i<4;++i)
          #pragma unroll
          for (int j=0;j<8;++j) ea[i][j] += a[i]*((j<4)?blo[j&3]:bhi[j&3]);
      }
    }
    __syncthreads();
  }

  // ---- epilogue: e (transposed global write), eT, wq + wq_a partials ----
  float ev[4][8];
  #pragma unroll
  for (int i=0;i<4;++i)
    #pragma unroll
    for (int j=0;j<8;++j) ev[i][j] = leaky(ea[i][j] + sm[12096 + PJ(j)]);

  {
    float* erow = e_wsT + (size_t)bd * 4096;
    #pragma unroll
    for (int j=0;j<8;++j) {
      f4 v = {ev[0][j],ev[1][j],ev[2][j],ev[3][j]};
      *(f4*)&erow[PJ(j)*64 + 4*tx] = v;       // e_wsT[bd][o][s]
    }
  }
  #pragma unroll
  for (int j=0;j<8;++j) {
    int o = PJ(j);
    f4 v = {ev[0][j],ev[1][j],ev[2][j],ev[3][j]};
    *(f4*)&sm[z*4352 + o*68 + 4*tx] = v;      // eT over f1T
  }
  #pragma unroll
  for (int i=0;i<4;++i) {
    float p = 0.f, pa = 0.f;
    #pragma unroll
    for (int j=0;j<8;++j) {
      p  += ev[i][j]*sm[12160 + PJ(j)];
      pa += ev[i][j]*sm[12368 + PJ(j)];
    }
    p += __shfl_xor(p, 16);  p += __shfl_xor(p, 32);
    pa += __shfl_xor(pa, 16); pa += __shfl_xor(pa, 32);
    if ((ty & 3) == 0) {
      sm[11520 + z*128 + wz*64 + 4*tx + i] = p;
      sm[12432 + z*128 + wz*64 + 4*tx + i] = pa;
    }
  }
  {
    const f4* s4 = (const f4*)(wv1T_all + (size_t)d*2304);
    f4 a0 = s4[tid], a1 = s4[tid+256];
    ((f4*)&sm[8704])[tid] = a0;
    ((f4*)&sm[8704])[tid+256] = a1;
    if (tid < 64) ((f4*)&sm[8704])[tid+512] = s4[tid+512];
  }
  __syncthreads();

  // ---- wq + wq_a-partial reduce ----
  if (tid < 128) {
    int z2 = tid >> 6, r = tid & 63;
    float p = sm[11520 + z2*128 + r] + sm[11520 + z2*128 + 64 + r];
    wq2_ws[((size_t)(b0+z2)*64 + r)*Dv + d] = sigm(p + bq0);
    float pa = sm[12432 + z2*128 + r] + sm[12432 + z2*128 + 64 + r];
    wqa_p[((size_t)(b0+z2)*64 + r)*Dv + d] = pa;
  }

  // ---- v-GEMM: va[s=4tx+i][h=4ty+j], K=64 ----
  float va[4][4];
  #pragma unroll
  for (int i=0;i<4;++i)
    #pragma unroll
    for (int j=0;j<4;++j) va[i][j]=0.f;
  #pragma unroll 8
  for (int o = 0; o < 64; ++o) {
    f4 a  = *(const f4*)&sm[z*4352 + o*68 + 4*tx];
    f4 bb = *(const f4*)&sm[8704 + o*36 + 4*ty];
    #pragma unroll
    for (int i=0;i<4;++i)
      #pragma unroll
      for (int j=0;j<4;++j) va[i][j] += a[i]*bb[j];
  }
  #pragma unroll
  for (int i=0;i<4;++i)
    #pragma unroll
    for (int j=0;j<4;++j) va[i][j] += sm[12240 + 4*ty + j];

  // ---- LN partials via wave shuffle ----
  #pragma unroll
  for (int i=0;i<4;++i) {
    float ps=0.f, pq=0.f;
    #pragma unroll
    for (int j=0;j<4;++j) { ps += va[i][j]; pq += va[i][j]*va[i][j]; }
    ps += __shfl_xor(ps, 16); ps += __shfl_xor(ps, 32);
    pq += __shfl_xor(pq, 16); pq += __shfl_xor(pq, 32);
    if ((ty & 3) == 0) {
      sm[11008 + z*128 + wz*64 + 4*tx + i] = ps;
      sm[11264 + z*128 + wz*64 + 4*tx + i] = pq;
    }
  }
  __syncthreads();
  if (tid < 128) {
    int z2 = tid >> 6, r = tid & 63;
    float s_ = sm[11008 + z2*128 + r] + sm[11008 + z2*128 + 64 + r];
    float q_ = sm[11264 + z2*128 + r] + sm[11264 + z2*128 + 64 + r];
    float mu = s_*(1.f/32.f);
    float vr = q_*(1.f/32.f) - mu*mu;
    sm[11776 + z2*64 + r] = mu;
    sm[11904 + z2*64 + r] = rsqrtf(vr + EPSv);
  }
  __syncthreads();

  // ---- LN + wv partials ----
  #pragma unroll
  for (int i=0;i<4;++i) {
    float mu = sm[11776 + z*64 + 4*tx + i];
    float rs = sm[11904 + z*64 + 4*tx + i];
    float p = 0.f;
    #pragma unroll
    for (int j=0;j<4;++j) {
      int h = 4*ty + j;
      float vh = leaky(sm[12272+h]*(va[i][j]-mu)*rs + sm[12304+h]);
      p += vh*sm[12336+h];
    }
    p += __shfl_xor(p, 16);
    p += __shfl_xor(p, 32);
    if ((ty & 3) == 0) sm[11520 + z*128 + wz*64 + 4*tx + i] = p;
  }
  __syncthreads();
  if (tid < 128) {
    int z2 = tid >> 6, r = tid & 63;
    float p = sm[11520 + z2*128 + r] + sm[11520 + z2*128 + 64 + r];
    wv_ws[((size_t)((b0+z2)*Dv + d))*64 + r] = fmaxf(p + bv2[d], 0.f);
  }
#undef PJ
}

// ---------------- K2: fused Wb1+LN+Wb2+cumsum+Wk/wq -> score1 ----------------
// 256 thr / 4 waves, 2 (b,d) pairs. Linear f4 staging (e_wsT/wb1T/wb2T/wkT),
// atomic LDS LN partials. LDS 51,456 B -> 3 blocks/CU (12 waves).
__global__ __launch_bounds__(256) void k2_fused(
    const float* __restrict__ e_wsT,
    const float* __restrict__ wb1T, const float* __restrict__ bb1,
    const float* __restrict__ lng, const float* __restrict__ lnb,
    const float* __restrict__ wb2T, const float* __restrict__ bb2,
    const float* __restrict__ wkT, const float* __restrict__ bk,
    const float* __restrict__ wq2_ws, float* __restrict__ score1)
{
  __shared__ float smem[12864];           // 50.25 KiB
  float* bufA = smem;                     // [64][132]: EsT -> HnT -> AcmlT
  float* bufB = smem + 8448;              // [4096]: W1T -> W2T -> WkT[64][40]
  float* pts  = smem + 12544;             // [128] atomic (then pt2)
  float* ptq  = smem + 12704;             // [128] atomic

  const int tid = threadIdx.x;
  const int tx = tid & 31;                // rows 4tx..4tx+3
  const int ty = tid >> 5;                // 0..7 -> cols
  const int lane = tid & 63;
  const int bd0 = blockIdx.x * 2;
  const int bd1 = bd0 + 1;

#define PJ(j) ((j) < 4 ? 4*ty + (j) : 32 + 4*ty + ((j)-4))

  if (tid < 128) { pts[tid] = 0.f; ptq[tid] = 0.f; }

  // ---- prefetch W2T (4 f4, written after B1) ----
  f4 w2r[4];
  {
    const f4* s4 = (const f4*)wb2T;
    #pragma unroll
    for (int q = 0; q < 4; ++q) w2r[q] = s4[tid + 256*q];
  }

  // ---- stage EsT (linear f4), W1T (linear f4) ----
  {
    const f4* Esrc = (const f4*)(e_wsT + (size_t)bd0 * 4096);
    #pragma unroll
    for (int m = 0; m < 8; ++m) {
      int n = tid + 256*m;                // 0..2047
      int o = n >> 5, t5 = n & 31;
      int z = t5 >> 4, sg = t5 & 15;
      *(f4*)&bufA[o*132 + z*64 + 4*sg] = Esrc[z*1024 + o*16 + sg];
    }
    const f4* W1s = (const f4*)wb1T;
    #pragma unroll
    for (int m = 0; m < 4; ++m) {
      int n = tid + 256*m;
      ((f4*)bufB)[n] = W1s[n];
    }
  }
  __syncthreads();                               // B0

  // per-thread column constants
  float bb1v[8], lngv[8], lnbv[8], bb2v[8];
  #pragma unroll
  for (int j=0;j<8;++j) {
    int p = PJ(j);
    bb1v[j]=bb1[p]; lngv[j]=lng[p]; lnbv[j]=lnb[p]; bb2v[j]=bb2[p];
  }

  // ---- GEMM1: h[r][p] = sum_o E[r][o]*Wb1[p][o], 4x8 tile ----
  float h[4][8];
  #pragma unroll
  for (int i=0;i<4;++i)
    #pragma unroll
    for (int j=0;j<8;++j) h[i][j]=0.f;
  for (int o = 0; o < 64; ++o) {
    f4 a  = *(const f4*)(bufA + o*132 + 4*tx);
    f4 bl = *(const f4*)(bufB + o*64 + 4*ty);
    f4 bh = *(const f4*)(bufB + o*64 + 32 + 4*ty);
    #pragma unroll
    for (int i=0;i<4;++i)
      #pragma unroll
      for (int j=0;j<8;++j) h[i][j] += a[i]*((j<4)?bl[j&3]:bh[j&3]);
  }
  #pragma unroll
  for (int i=0;i<4;++i)
    #pragma unroll
    for (int j=0;j<8;++j) h[i][j] += bb1v[j];

  // ---- LN partials: shfl ty-pair, atomic add into pts/ptq ----
  #pragma unroll
  for (int i=0;i<4;++i) {
    float ps=0.f, pq=0.f;
    #pragma unroll
    for (int j=0;j<8;++j) { ps += h[i][j]; pq += h[i][j]*h[i][j]; }
    ps += __shfl_xor(ps, 32);
    pq += __shfl_xor(pq, 32);
    if (lane < 32) {
      atomicAdd(&pts[4*tx+i], ps);
      atomicAdd(&ptq[4*tx+i], pq);
    }
  }
  __syncthreads();                               // B1

  // ---- read stats, normalize + leaky, HnT f4 write; W2T write ----
  {
    #pragma unroll
    for (int q = 0; q < 4; ++q) ((f4*)bufB)[tid + 256*q] = w2r[q];
  }
  {
    float muv[4], rsv[4];
    #pragma unroll
    for (int i=0;i<4;++i) {
      float s = pts[4*tx+i], q = ptq[4*tx+i];
      float mu = s*(1.f/64.f);
      float va = q*(1.f/64.f) - mu*mu;
      muv[i] = mu; rsv[i] = rsqrtf(va + EPSv);
    }
    #pragma unroll
    for (int j=0;j<8;++j) {
      f4 v;
      #pragma unroll
      for (int i=0;i<4;++i)
        v[i] = leaky(lngv[j]*(h[i][j]-muv[i])*rsv[i] + lnbv[j]);
      *(f4*)&bufA[PJ(j)*132 + 4*tx] = v;
    }
  }
  __syncthreads();                               // B2

  // zero pt2 region for epilogue
  if (tid < 128) pts[tid] = 0.f;

  // ---- GEMM2: g[r][q] = sum_p Hn[r][p]*Wb2[q][p] ----
  float g[4][8];
  #pragma unroll
  for (int i=0;i<4;++i)
    #pragma unroll
    for (int j=0;j<8;++j) g[i][j]=0.f;
  for (int p = 0; p < 64; ++p) {
    f4 a  = *(const f4*)(bufA + p*132 + 4*tx);
    f4 bl = *(const f4*)(bufB + p*64 + 4*ty);
    f4 bh = *(const f4*)(bufB + p*64 + 32 + 4*ty);
    #pragma unroll
    for (int i=0;i<4;++i)
      #pragma unroll
      for (int j=0;j<8;++j) g[i][j] += a[i]*((j<4)?bl[j&3]:bh[j&3]);
  }
  #pragma unroll
  for (int i=0;i<4;++i)
    #pragma unroll
    for (int j=0;j<8;++j) g[i][j] = leaky(g[i][j] + bb2v[j]);

  // ---- cumsum over s via 16-lane segment scan ----
  #pragma unroll
  for (int j=0;j<8;++j) {
    float c0_=g[0][j], c1=c0_+g[1][j], c2=c1+g[2][j], c3=c2+g[3][j];
    float incl = c3;
    #pragma unroll
    for (int dd=1; dd<16; dd<<=1) {
      float t = __shfl_up(incl, dd, 16);
      if ((tid & 15) >= dd) incl += t;
    }
    float ex = incl - c3;
    g[0][j]=ex+c0_; g[1][j]=ex+c1; g[2][j]=ex+c2; g[3][j]=ex+c3;
  }

  // ---- Wk prefetch (linear) ----
  float wkr[10];
  #pragma unroll
  for (int n = 0; n < 10; ++n) wkr[n] = wkT[tid + 256*n];
  __syncthreads();                               // B3

  // ---- write AcmlT f4; WkT linear ----
  #pragma unroll
  for (int j=0;j<8;++j) {
    f4 v = {g[0][j], g[1][j], g[2][j], g[3][j]};
    *(f4*)&bufA[PJ(j)*132 + 4*tx] = v;
  }
  #pragma unroll
  for (int n = 0; n < 10; ++n) bufB[tid + 256*n] = wkr[n];
  __syncthreads();                               // B4

  // ---- GEMM3: u[r][k] = sum_q acml[r][q]*Wk[k][q] (k<38) ----
  float u[4][4], u2[4][4];
  #pragma unroll
  for (int i=0;i<4;++i)
    #pragma unroll
    for (int j=0;j<4;++j) { u[i][j]=0.f; u2[i][j]=0.f; }
  for (int q = 0; q < 64; ++q) {
    f4 a   = *(const f4*)(bufA + q*132 + 4*tx);
    f4 b1v = *(const f4*)(bufB + q*40 + 4*ty);
    #pragma unroll
    for (int i=0;i<4;++i)
      #pragma unroll
      for (int j=0;j<4;++j) u[i][j] += a[i]*b1v[j];
    if (ty < 2) {
      f4 b2v = *(const f4*)(bufB + q*40 + 32 + 4*ty);
      #pragma unroll
      for (int i=0;i<4;++i)
        #pragma unroll
        for (int j=0;j<4;++j) u2[i][j] += a[i]*b2v[j];
    }
  }

  // ---- epilogue: sigm(u+bk)*wq, shfl + atomic -> pt2(pts) ----
  const int b0g = bd0/Dv, d0g = bd0%Dv, b1g = bd1/Dv, d1g = bd1%Dv;
  #pragma unroll
  for (int i=0;i<4;++i) {
    int r = 4*tx + i;
    int s = r & 63;
    int bb_ = (r >> 6) ? b1g : b0g;
    const float* wqrow = wq2_ws + ((size_t)bb_*Sv + s)*Dv;
    float p = 0.f;
    #pragma unroll
    for (int j=0;j<4;++j) {
      int k = 4*ty + j;
      p += sigm(u[i][j] + bk[k]) * wqrow[k];
    }
    if (ty < 2) {
      #pragma unroll
      for (int j=0;j<4;++j) {
        int k = 32 + 4*ty + j;
        if (k < Dv) p += sigm(u2[i][j] + bk[k]) * wqrow[k];
      }
    }
    p += __shfl_xor(p, 32);
    if (lane < 32) atomicAdd(&pts[r], p);
  }
  __syncthreads();                               // B5
  if (tid < 128) {
    float tot = pts[tid];
    int grp = tid >> 6, s = tid & 63;
    int bb_ = grp ? b1g : b0g;
    int dd_ = grp ? d1g : d0g;
    score1[((size_t)bb_*Sv + s)*Dv + dd_] = tot;
  }
#undef PJ
}

// ---------------- K3: att1 softmax + contributes1/output1 + wq_a (64 thr) ----------------
__global__ __launch_bounds__(64) void k3_att1(
    const float* __restrict__ score1, const float* __restrict__ wv_ws,
    const float* __restrict__ wqa_p, const float* __restrict__ bq2,
    float* __restrict__ out_c1, float* __restrict__ output1, float* __restrict__ wq_a)
{
  const int blk = blockIdx.x;
  const int b = blk / Sv, s = blk % Sv;
  const int lane = threadIdx.x;

  const float invsq = 0.16222142113076254f; // 1/sqrt(38)
  float sc = (lane<Dv) ? score1[(b*Sv+s)*Dv+lane]*invsq : -1e30f;
  float mx = wmax64(sc);
  float ex = (lane<Dv) ? expf(sc-mx) : 0.f;
  float den = wred64(ex);
  float att = ex/den;
  float c1 = 0.f;
  if (lane<Dv) {
    c1 = wv_ws[(b*Dv+lane)*Sv+s]*att;
    out_c1[(b*Sv+s)*Dv+lane] = c1;
  }
  float tot = wred64(c1);
  if (lane==0) output1[b*Sv+s] = tot;

  float p = (lane < Dv) ? wqa_p[((size_t)b*Sv + s)*Dv + lane] : 0.f;
  p = wred64(p);
  if (lane==0) wq_a[b*Sv+s] = sigm(p + bq2[0]);
}

// ---------------- K4: per-b 64x64x2432 GEMM + fused score2 ----------------
__global__ __launch_bounds__(256) void k4_gemm(
    const float* __restrict__ e_wsT, const float* __restrict__ wk2T,
    const float* __restrict__ bk2,
    const float* __restrict__ wq_a, float* __restrict__ score2)
{
  const int b = blockIdx.x;
  const int tid = threadIdx.x;
  const int tx = tid & 15, ty = tid >> 4;       // tile coords
  __shared__ float AsT[64*68];
  __shared__ float BsT[64*68];
  __shared__ float pt[64*17];

  float acc[4][4];
  #pragma unroll
  for (int i=0;i<4;++i)
    #pragma unroll
    for (int j=0;j<4;++j) acc[i][j]=0.f;

  for (int d = 0; d < 38; ++d) {
    const f4* Asrc = (const f4*)(e_wsT + ((size_t)(b*Dv+d))*4096);
    const f4* Bsrc = (const f4*)(wk2T + (size_t)d*4096);
    #pragma unroll
    for (int m = 0; m < 4; ++m) {
      int n = tid + 256*m;                 // 0..1023
      int o = n >> 4, sg = n & 15;
      *(f4*)&AsT[o*68 + 4*sg] = Asrc[n];
      *(f4*)&BsT[o*68 + 4*sg] = Bsrc[n];
    }
    __syncthreads();
    #pragma unroll 4
    for (int o = 0; o < 64; ++o) {
      f4 a  = *(const f4*)&AsT[o*68 + 4*tx];
      f4 bb = *(const f4*)&BsT[o*68 + 4*ty];
      #pragma unroll
      for (int i=0;i<4;++i)
        #pragma unroll
        for (int j=0;j<4;++j) acc[i][j] += a[i]*bb[j];
    }
    __syncthreads();
  }

  // epilogue: score2[b,t] = sum_s sigm(C[t,s]+bk2[s])*wq_a[b,s]
  #pragma unroll
  for (int i=0;i<4;++i) {
    float p = 0.f;
    #pragma unroll
    for (int j=0;j<4;++j) {
      int s = 4*ty + j;
      p += sigm(acc[i][j] + bk2[s]) * wq_a[b*Sv + s];
    }
    pt[(4*tx+i)*17 + ty] = p;
  }
  __syncthreads();
  if (tid < 64) {
    float tot = 0.f;
    #pragma unroll
    for (int y=0;y<16;++y) tot += pt[tid*17+y];
    score2[b*Sv + tid] = tot;
  }
}

// ---------------- K5: att2 softmax + contributes2/output2 ----------------
__global__ __launch_bounds__(64) void k5_final(
    const float* __restrict__ score2, const float* __restrict__ output1,
    float* __restrict__ out)
{
  const int b = blockIdx.x;
  const int lane = threadIdx.x;
  const float inv = 0.039528470752104741f; // 1/sqrt(640)
  float v = score2[b*Sv+lane]*inv;
  float mx = wmax64(v);
  float ex = expf(v-mx);
  float den = wred64(ex);
  float att = ex/den;
  float c2 = output1[b*Sv+lane]*att;
  out[256 + b*Sv + lane] = c2;     // contributes2
  float tot = wred64(c2);
  if (lane==0) out[b] = tot;       // output2
}

extern "C" void kernel_launch(void* const* d_in, const int* in_sizes, int n_in,
                              void* d_out, int out_size, void* d_ws, size_t ws_size,
                              hipStream_t stream)
{
  const float* x    = (const float*)d_in[0];
  const float* W1   = (const float*)d_in[1];
  const float* b1   = (const float*)d_in[2];
  const float* W2   = (const float*)d_in[3];
  const float* b2   = (const float*)d_in[4];
  const float* Wl   = (const float*)d_in[5];
  const float* bl   = (const float*)d_in[6];
  const float* Wb1  = (const float*)d_in[7];
  const float* bb1  = (const float*)d_in[8];
  const float* lng  = (const float*)d_in[9];
  const float* lnb  = (const float*)d_in[10];
  const float* Wb2  = (const float*)d_in[11];
  const float* bb2  = (const float*)d_in[12];
  const float* Wq   = (const float*)d_in[13];
  const float* bq   = (const float*)d_in[14];
  const float* Wk   = (const float*)d_in[15];
  const float* bk   = (const float*)d_in[16];
  const float* Wv1  = (const float*)d_in[17];
  const float* bv1  = (const float*)d_in[18];
  const float* lnvg = (const float*)d_in[19];
  const float* lnvb = (const float*)d_in[20];
  const float* Wv2  = (const float*)d_in[21];
  const float* bv2  = (const float*)d_in[22];
  const float* Wq2  = (const float*)d_in[23];
  const float* bq2  = (const float*)d_in[24];
  const float* Wk2  = (const float*)d_in[25];
  const float* bk2  = (const float*)d_in[26];

  float* ws = (float*)d_ws;
  float* e_wsT = ws;                                   // B*D*S*64
  float* wq2w  = e_wsT + (size_t)Bv*Dv*Sv*64;          // B*S*D
  float* wv_ws = wq2w + (size_t)Bv*Sv*Dv;              // B*D*S
  float* sc1   = wv_ws + (size_t)Bv*Dv*Sv;             // B*S*D
  float* out1  = sc1 + (size_t)Bv*Sv*Dv;               // B*S
  float* wqa   = out1 + (size_t)Bv*Sv;                 // B*S
  float* sc2   = wqa + (size_t)Bv*Sv;                  // B*S
  float* wlT   = sc2 + (size_t)Bv*Sv;                  // 330752
  float* w1T   = wlT + 330752;                         // 25840
  float* wv1T  = w1T + 25840;                          // 87552
  float* wqap  = wv1T + 87552;                         // B*S*D = 622592
  float* wb1T  = wqap + (size_t)Bv*Sv*Dv;              // 4096
  float* wb2T  = wb1T + 4096;                          // 4096
  float* wkT   = wb2T + 4096;                          // 2560
  float* wk2T  = wkT + 2560;                           // 155648

  float* out = (float*)d_out;
  float* out_c1 = out + 256 + Bv*Sv;                   // contributes1 offset

  hipLaunchKernelGGL(k0_pack, dim3(2385), dim3(256), 0, stream,
    Wl, W1, Wv1, Wb1, Wb2, Wk, Wk2, wlT, w1T, wv1T, wb1T, wb2T, wkT, wk2T);
  hipLaunchKernelGGL(k1_fe4, dim3(Dv*128), dim3(256), 0, stream,
    x, w1T, b1, W2, b2, wlT, bl, Wq, bq, wv1T, bv1, lnvg, lnvb, Wv2, bv2,
    Wq2, e_wsT, wq2w, wv_ws, wqap);
  hipLaunchKernelGGL(k2_fused, dim3(Bv*Dv/2), dim3(256), 0, stream,
    e_wsT, wb1T, bb1, lng, lnb, wb2T, bb2, wkT, bk, wq2w, sc1);
  hipLaunchKernelGGL(k3_att1, dim3(Bv*Sv), dim3(64), 0, stream,
    sc1, wv_ws, wqap, bq2, out_c1, out1, wqa);
  hipLaunchKernelGGL(k4_gemm, dim3(Bv), dim3(256), 0, stream,
    e_wsT, wk2T, bk2, wqa, sc2);
  hipLaunchKernelGGL(k5_final, dim3(Bv), dim3(64), 0, stream, sc2, out1, out);
}